// Round 2
// baseline (2320.253 us; speedup 1.0000x reference)
//
#include <hip/hip_runtime.h>

// DoubleAttention: B=1024, S_OUT=30, S_IN=17, D_IN=3, H=4
// inner: dkq=6 dv=8 hid=256 out=64 ; outer: dkq=dv=64 hid=1024 out=1080
//
// ws layout (floats):
//   flat_i : [30720][544]  @ 0          (dead after K2; region reused)
//   seq    : [30720][64]   @ 16711680
//   ctx_o  : [4096][1920]  @ 0          (reuse of flat region)
//   hout   : [4096][1024]  @ 8000000
// total ws need = 18,677,760 floats = 74.7 MB

__device__ inline float tanh_fast(float x) {
    float ax = fabsf(x);
    float e  = __expf(2.0f * ax);
    float r  = 1.0f - 2.0f / (e + 1.0f);   // safe for large |x| (-> 1)
    return copysignf(r, x);
}

// ---------------- K1: inner attention -> flat[bs][h*136 + p*8 + dv] ----------
__global__ __launch_bounds__(64) void k_inner_attn(
    const float* __restrict__ x,
    const float* __restrict__ iwq, const float* __restrict__ ibq,
    const float* __restrict__ iwk, const float* __restrict__ ibk,
    const float* __restrict__ iwv, const float* __restrict__ ibv,
    float* __restrict__ flat_out)
{
    __shared__ float xl[51];
    __shared__ float ql[4][17][6];
    __shared__ float kl[4][17][6];
    __shared__ float vl[4][17][8];
    __shared__ float al[4][17][17];
    const int bs = blockIdx.x;           // b*30 + s
    const int t  = threadIdx.x;
    if (t < 51) xl[t] = x[bs * 51 + t];
    __syncthreads();
    for (int idx = t; idx < 68; idx += 64) {
        const int h = idx / 17, p = idx % 17;
        const float x0 = xl[p*3+0], x1 = xl[p*3+1], x2 = xl[p*3+2];
        #pragma unroll
        for (int d = 0; d < 6; d++) {
            ql[h][p][d] = ibq[h*6+d] + x0*iwq[(h*3+0)*6+d] + x1*iwq[(h*3+1)*6+d] + x2*iwq[(h*3+2)*6+d];
            kl[h][p][d] = ibk[h*6+d] + x0*iwk[(h*3+0)*6+d] + x1*iwk[(h*3+1)*6+d] + x2*iwk[(h*3+2)*6+d];
        }
        #pragma unroll
        for (int d = 0; d < 8; d++) {
            vl[h][p][d] = ibv[h*8+d] + x0*iwv[(h*3+0)*8+d] + x1*iwv[(h*3+1)*8+d] + x2*iwv[(h*3+2)*8+d];
        }
    }
    __syncthreads();
    for (int idx = t; idx < 68; idx += 64) {
        const int h = idx / 17, p = idx % 17;
        float sc[17];
        float mx = -1e30f;
        #pragma unroll
        for (int j = 0; j < 17; j++) {
            float s = 0.f;
            #pragma unroll
            for (int d = 0; d < 6; d++) s += ql[h][p][d] * kl[h][j][d];
            s *= 0.40824829046386307f;   // 1/sqrt(6)
            sc[j] = s; mx = fmaxf(mx, s);
        }
        float sum = 0.f;
        #pragma unroll
        for (int j = 0; j < 17; j++) { float e = __expf(sc[j] - mx); sc[j] = e; sum += e; }
        const float inv = 1.0f / sum;
        #pragma unroll
        for (int j = 0; j < 17; j++) al[h][p][j] = sc[j] * inv;
    }
    __syncthreads();
    float* fo = flat_out + bs * 544;
    for (int idx = t; idx < 544; idx += 64) {
        const int h = idx / 136; const int r = idx - h * 136;
        const int p = r >> 3, dv = r & 7;
        float acc = 0.f;
        #pragma unroll
        for (int j = 0; j < 17; j++) acc += al[h][p][j] * vl[h][j][dv];
        fo[idx] = acc;
    }
}

// ---------------- K2: inner ML (fc1+tanh+fc2), 8 (b,s) pairs per block -------
// FIX vs round 1: fc1 column coverage. Wave g handles samples {g, g+4}; a wave
// has 64 lanes, so lane l must cover hidden cols {l, l+64, l+128, l+192}.
// (Round 1 used block-wide t as the column -> 3/4 of h1l never written.)
__global__ __launch_bounds__(256) void k_inner_ml(
    const float* __restrict__ flat,
    const float* __restrict__ iw1, const float* __restrict__ ib1,
    const float* __restrict__ iw2, const float* __restrict__ ib2,
    float* __restrict__ seq)
{
    __shared__ float h1l[8][1024];
    __shared__ float red[8][8][64];
    const int t    = threadIdx.x;
    const int base = blockIdx.x * 8;
    const int l    = t & 63;
    const int g    = __builtin_amdgcn_readfirstlane(t >> 6);  // wave id -> SGPR (scalarize flat reads)
    float acc[2][4][4];   // [pair][head][colchunk]
    #pragma unroll
    for (int ci = 0; ci < 4; ci++) {
        const float b1 = ib1[ci*64 + l];
        #pragma unroll
        for (int pp = 0; pp < 2; pp++)
            #pragma unroll
            for (int hh = 0; hh < 4; hh++) acc[pp][hh][ci] = b1;
    }
    const float* fr0 = flat + (size_t)(base + g)     * 544;
    const float* fr1 = flat + (size_t)(base + g + 4) * 544;
    for (int k = 0; k < 136; k++) {
        float w[4];
        #pragma unroll
        for (int ci = 0; ci < 4; ci++) w[ci] = iw1[k*256 + ci*64 + l];
        #pragma unroll
        for (int hh = 0; hh < 4; hh++) {
            const float f0 = fr0[hh*136 + k];   // wave-uniform -> s_load
            const float f1 = fr1[hh*136 + k];
            #pragma unroll
            for (int ci = 0; ci < 4; ci++) {
                acc[0][hh][ci] += f0 * w[ci];
                acc[1][hh][ci] += f1 * w[ci];
            }
        }
    }
    #pragma unroll
    for (int pp = 0; pp < 2; pp++)
        #pragma unroll
        for (int hh = 0; hh < 4; hh++)
            #pragma unroll
            for (int ci = 0; ci < 4; ci++)
                h1l[g + pp*4][hh*256 + ci*64 + l] = tanh_fast(acc[pp][hh][ci]);
    __syncthreads();
    // fc2: 2 outputs per thread, 8-way k-split
    const int o2 = (t & 31) * 2;
    const int kq = t >> 5;
    float a2[8][2];
    #pragma unroll
    for (int p = 0; p < 8; p++) { a2[p][0] = 0.f; a2[p][1] = 0.f; }
    for (int k = kq * 128; k < kq * 128 + 128; k++) {
        const float2 w = *(const float2*)&iw2[k * 64 + o2];
        #pragma unroll
        for (int p = 0; p < 8; p++) {
            const float hv = h1l[p][k];
            a2[p][0] += hv * w.x; a2[p][1] += hv * w.y;
        }
    }
    #pragma unroll
    for (int p = 0; p < 8; p++)
        *(float2*)&red[kq][p][o2] = make_float2(a2[p][0], a2[p][1]);
    __syncthreads();
    for (int idx = t; idx < 512; idx += 256) {
        const int p = idx >> 6, o = idx & 63;
        float s = ib2[o];
        #pragma unroll
        for (int q = 0; q < 8; q++) s += red[q][p][o];
        seq[(size_t)(base + p) * 64 + o] = s;
    }
}

// ---------------- K3: outer attention, one block per (b,h) -------------------
__device__ inline void proj30x64(const float (*sl)[64], const float* __restrict__ w,
                                 float bias, int d, int g, float (*outl)[64])
{
    float acc[8];
    #pragma unroll
    for (int i = 0; i < 8; i++) acc[i] = bias;
    for (int dd = 0; dd < 64; dd += 4) {
        const float w0 = w[(dd+0)*64 + d];
        const float w1 = w[(dd+1)*64 + d];
        const float w2 = w[(dd+2)*64 + d];
        const float w3 = w[(dd+3)*64 + d];
        #pragma unroll
        for (int i = 0; i < 8; i++) {
            const int p = g + i * 4;
            if (p < 30) {
                const float4 s4 = *(const float4*)&sl[p][dd];
                acc[i] += s4.x*w0 + s4.y*w1 + s4.z*w2 + s4.w*w3;
            }
        }
    }
    #pragma unroll
    for (int i = 0; i < 8; i++) { const int p = g + i * 4; if (p < 30) outl[p][d] = acc[i]; }
}

__global__ __launch_bounds__(256) void k_outer_attn(
    const float* __restrict__ seq,
    const float* __restrict__ owq, const float* __restrict__ obq,
    const float* __restrict__ owk, const float* __restrict__ obk,
    const float* __restrict__ owv, const float* __restrict__ obv,
    float* __restrict__ ctxo)
{
    __shared__ float sl[30][64];
    __shared__ float ql[30][64];
    __shared__ float kl[30][64];
    __shared__ float vl[30][64];
    __shared__ float al[30][30];
    const int bh = blockIdx.x, b = bh >> 2, h = bh & 3;
    const int t = threadIdx.x;
    const float* sb = seq + (size_t)b * 1920;
    for (int i = t; i < 1920; i += 256) ((float*)sl)[i] = sb[i];
    __syncthreads();
    const int d = t & 63, g = t >> 6;
    proj30x64(sl, owq + h*4096, obq[h*64 + d], d, g, ql);
    proj30x64(sl, owk + h*4096, obk[h*64 + d], d, g, kl);
    proj30x64(sl, owv + h*4096, obv[h*64 + d], d, g, vl);
    __syncthreads();
    for (int idx = t; idx < 900; idx += 256) {
        const int p = idx / 30, q = idx - p * 30;
        float s = 0.f;
        for (int dd = 0; dd < 64; dd += 4) {
            const float4 a4 = *(const float4*)&ql[p][dd];
            const float4 b4 = *(const float4*)&kl[q][dd];
            s += a4.x*b4.x + a4.y*b4.y + a4.z*b4.z + a4.w*b4.w;
        }
        al[p][q] = s * 0.125f;           // 1/sqrt(64)
    }
    __syncthreads();
    if (t < 30) {
        float mx = -1e30f;
        for (int q = 0; q < 30; q++) mx = fmaxf(mx, al[t][q]);
        float sum = 0.f;
        for (int q = 0; q < 30; q++) { float e = __expf(al[t][q] - mx); al[t][q] = e; sum += e; }
        const float inv = 1.0f / sum;
        for (int q = 0; q < 30; q++) al[t][q] *= inv;
    }
    __syncthreads();
    float* co = ctxo + (size_t)bh * 1920;
    for (int idx = t; idx < 1920; idx += 256) {
        const int p = idx >> 6, dd = idx & 63;
        float acc = 0.f;
        #pragma unroll
        for (int q = 0; q < 30; q++) acc += al[p][q] * vl[q][dd];
        co[idx] = acc;
    }
}

// ---------------- K4: outer fc1 + tanh : [4096,1920]x[1920,1024] -------------
__global__ __launch_bounds__(256) void k_outer_fc1(
    const float* __restrict__ ctxo, const float* __restrict__ ow1,
    const float* __restrict__ ob1, float* __restrict__ hout)
{
    const int nbi = blockIdx.x & 3;
    const int m0  = (blockIdx.x >> 2) * 16;
    const int n   = nbi * 256 + threadIdx.x;
    float acc[16];
    const float bias = ob1[n];
    #pragma unroll
    for (int i = 0; i < 16; i++) acc[i] = bias;
    for (int k = 0; k < 1920; k++) {
        const float w = ow1[(size_t)k * 1024 + n];
        #pragma unroll
        for (int i = 0; i < 16; i++)
            acc[i] += ctxo[(size_t)(m0 + i) * 1920 + k] * w;   // uniform -> s_load
    }
    #pragma unroll
    for (int i = 0; i < 16; i++)
        hout[(size_t)(m0 + i) * 1024 + n] = tanh_fast(acc[i]);
}

// ---------------- K5: outer fc2 : [1024,4096]x[4096,1080] --------------------
__global__ __launch_bounds__(256) void k_outer_fc2(
    const float* __restrict__ hout, const float* __restrict__ ow2,
    const float* __restrict__ ob2, float* __restrict__ out)
{
    __shared__ float red[4][16][64];
    const int nbi = blockIdx.x % 17;
    const int m0  = (blockIdx.x / 17) * 16;
    const int t   = threadIdx.x;
    const int nl  = t & 63, kq = t >> 6;
    const int n   = nbi * 64 + nl;
    const int nc  = n < 1080 ? n : 1079;
    float acc[16];
    #pragma unroll
    for (int i = 0; i < 16; i++) acc[i] = 0.f;
    for (int k = kq * 1024; k < kq * 1024 + 1024; k++) {
        const float w = ow2[(size_t)k * 1080 + nc];
        #pragma unroll
        for (int i = 0; i < 16; i++)
            acc[i] += hout[(size_t)(m0 + i) * 4096 + k] * w;   // uniform -> s_load
    }
    #pragma unroll
    for (int i = 0; i < 16; i++) red[kq][i][nl] = acc[i];
    __syncthreads();
    for (int idx = t; idx < 1024; idx += 256) {
        const int i = idx >> 6, nn = idx & 63;
        const int no = nbi * 64 + nn;
        if (no < 1080) {
            float s = red[0][i][nn] + red[1][i][nn] + red[2][i][nn] + red[3][i][nn] + ob2[no];
            out[(size_t)(m0 + i) * 1080 + no] = s;
        }
    }
}

extern "C" void kernel_launch(void* const* d_in, const int* in_sizes, int n_in,
                              void* d_out, int out_size, void* d_ws, size_t ws_size,
                              hipStream_t stream) {
    const float* x   = (const float*)d_in[0];
    const float* iwq = (const float*)d_in[1];
    const float* ibq = (const float*)d_in[2];
    const float* iwk = (const float*)d_in[3];
    const float* ibk = (const float*)d_in[4];
    const float* iwv = (const float*)d_in[5];
    const float* ibv = (const float*)d_in[6];
    const float* iw1 = (const float*)d_in[7];
    const float* ib1 = (const float*)d_in[8];
    const float* iw2 = (const float*)d_in[9];
    const float* ib2 = (const float*)d_in[10];
    const float* owq = (const float*)d_in[11];
    const float* obq = (const float*)d_in[12];
    const float* owk = (const float*)d_in[13];
    const float* obk = (const float*)d_in[14];
    const float* owv = (const float*)d_in[15];
    const float* obv = (const float*)d_in[16];
    const float* ow1 = (const float*)d_in[17];
    const float* ob1 = (const float*)d_in[18];
    const float* ow2 = (const float*)d_in[19];
    const float* ob2 = (const float*)d_in[20];

    float* ws   = (float*)d_ws;
    float* flat = ws;                 // [30720][544]
    float* seq  = ws + 16711680;      // [30720][64]
    float* ctxo = ws;                 // [4096][1920]  (reuses flat region)
    float* hout = ws + 8000000;       // [4096][1024]
    float* out  = (float*)d_out;

    k_inner_attn<<<dim3(30720), dim3(64), 0, stream>>>(x, iwq, ibq, iwk, ibk, iwv, ibv, flat);
    k_inner_ml  <<<dim3(3840),  dim3(256), 0, stream>>>(flat, iw1, ib1, iw2, ib2, seq);
    k_outer_attn<<<dim3(4096),  dim3(256), 0, stream>>>(seq, owq, obq, owk, obk, owv, obv, ctxo);
    k_outer_fc1 <<<dim3(1024),  dim3(256), 0, stream>>>(ctxo, ow1, ob1, hout);
    k_outer_fc2 <<<dim3(1088),  dim3(256), 0, stream>>>(hout, ow2, ob2, out);
}

// Round 3
// 625.209 us; speedup vs baseline: 3.7112x; 3.7112x over previous
//
#include <hip/hip_runtime.h>

// DoubleAttention: B=1024, S_OUT=30, S_IN=17, D_IN=3, H=4
// inner: dkq=6 dv=8 hid=256 out=64 ; outer: dkq=dv=64 hid=1024 out=1080
//
// Round 3: f16 MFMA (16x16x32) for all four GEMMs, fp32 accumulate.
//   MFMA layouts (verified, learn_hip m89/m91/m120):
//     A-frag: lane holds A[m=lane&15][k0 + (lane>>4)*8 + j], j=0..7 (16B load)
//     B-frag: lane holds B[k0 + (lane>>4)*8 + j][n=lane&15]  (load from Wt[n][k], 16B)
//     D:      acc[r] -> D[row=(lane>>4)*4+r][col=lane&15]
//
// ws layout (bytes):
//   iw1t  f16 [256][160]    @ 0           (K 136->160 zero-pad)
//   iw2t  f16 [64][1024]    @ 163,840
//   ow1t  f16 [1024][1920]  @ 294,912
//   ow2t  f16 [1088][4096]  @ 4,227,072   (N 1080->1088 zero-pad)
//   flat  f16 [122880][160] @ 13,139,968  (dead after G12; region reused)
//   seq   f32 [30720][64]   @ 52,461,568
//   ctxo  f16 [4096][1920]  @ 13,139,968  (reuse)
//   hout  f16 [1024][4096]  @ 28,868,608  (reuse)
// peak = 60.3 MB (<= 74.7 MB proven available in round 2)

typedef _Float16 f16x8 __attribute__((ext_vector_type(8)));
typedef float    f32x4 __attribute__((ext_vector_type(4)));

__device__ inline float tanh_fast(float x) {
    float ax = fabsf(x);
    float e  = __expf(2.0f * ax);
    float r  = 1.0f - 2.0f / (e + 1.0f);
    return copysignf(r, x);
}

// ---------------- weight transpose+cast: W[K][N] f32 -> Wt[Npad][Kpad] f16 ---
__global__ __launch_bounds__(256) void k_tcast(
    const float* __restrict__ W, _Float16* __restrict__ Wt,
    int K, int N, int Kpad, int Npad)
{
    int idx = blockIdx.x * 256 + threadIdx.x;
    if (idx >= Npad * Kpad) return;
    int n = idx / Kpad, k = idx - n * Kpad;
    float v = (k < K && n < N) ? W[k * N + n] : 0.0f;
    Wt[idx] = (_Float16)v;
}

// ---------------- K1: inner attention -> flat f16 [bs*4+h][160] (zero-pad) --
__global__ __launch_bounds__(64) void k_inner_attn(
    const float* __restrict__ x,
    const float* __restrict__ iwq, const float* __restrict__ ibq,
    const float* __restrict__ iwk, const float* __restrict__ ibk,
    const float* __restrict__ iwv, const float* __restrict__ ibv,
    _Float16* __restrict__ flat_out)
{
    __shared__ float xl[51];
    __shared__ float ql[4][17][6];
    __shared__ float kl[4][17][6];
    __shared__ float vl[4][17][8];
    __shared__ float al[4][17][17];
    const int bs = blockIdx.x;
    const int t  = threadIdx.x;
    if (t < 51) xl[t] = x[bs * 51 + t];
    __syncthreads();
    for (int idx = t; idx < 68; idx += 64) {
        const int h = idx / 17, p = idx % 17;
        const float x0 = xl[p*3+0], x1 = xl[p*3+1], x2 = xl[p*3+2];
        #pragma unroll
        for (int d = 0; d < 6; d++) {
            ql[h][p][d] = ibq[h*6+d] + x0*iwq[(h*3+0)*6+d] + x1*iwq[(h*3+1)*6+d] + x2*iwq[(h*3+2)*6+d];
            kl[h][p][d] = ibk[h*6+d] + x0*iwk[(h*3+0)*6+d] + x1*iwk[(h*3+1)*6+d] + x2*iwk[(h*3+2)*6+d];
        }
        #pragma unroll
        for (int d = 0; d < 8; d++)
            vl[h][p][d] = ibv[h*8+d] + x0*iwv[(h*3+0)*8+d] + x1*iwv[(h*3+1)*8+d] + x2*iwv[(h*3+2)*8+d];
    }
    __syncthreads();
    for (int idx = t; idx < 68; idx += 64) {
        const int h = idx / 17, p = idx % 17;
        float sc[17];
        float mx = -1e30f;
        #pragma unroll
        for (int j = 0; j < 17; j++) {
            float s = 0.f;
            #pragma unroll
            for (int d = 0; d < 6; d++) s += ql[h][p][d] * kl[h][j][d];
            s *= 0.40824829046386307f;
            sc[j] = s; mx = fmaxf(mx, s);
        }
        float sum = 0.f;
        #pragma unroll
        for (int j = 0; j < 17; j++) { float e = __expf(sc[j] - mx); sc[j] = e; sum += e; }
        const float inv = 1.0f / sum;
        #pragma unroll
        for (int j = 0; j < 17; j++) al[h][p][j] = sc[j] * inv;
    }
    __syncthreads();
    _Float16* fo = flat_out + (size_t)bs * 640;   // 4 heads * 160
    for (int idx = t; idx < 640; idx += 64) {
        const int h = idx / 160, r = idx - h * 160;
        float acc = 0.f;
        if (r < 136) {
            const int p = r >> 3, dv = r & 7;
            #pragma unroll
            for (int j = 0; j < 17; j++) acc += al[h][p][j] * vl[h][j][dv];
        }
        fo[idx] = (_Float16)acc;
    }
}

// ---------------- G12: inner ML fused (fc1+tanh -> LDS -> fc2), MFMA --------
// block = 256 thr = 4 waves, 32 bs-samples (128 rows of flat)
__global__ __launch_bounds__(256) void k_inner_ml_mfma(
    const _Float16* __restrict__ flat,   // [122880][160]
    const _Float16* __restrict__ iw1t,   // [256][160]
    const _Float16* __restrict__ iw2t,   // [64][1024]
    const float* __restrict__ ib1, const float* __restrict__ ib2,
    float* __restrict__ seq)             // [30720][64]
{
    __shared__ __align__(16) _Float16 h1l[32][1032];   // 66 KB, +8 pad (2-way banks, free)
    float* red = (float*)&h1l[0][0];                   // overlay: [4][32][64] f32 = 32 KB
    const int t = threadIdx.x, lane = t & 63, w = t >> 6;
    const int q = lane >> 4, ml = lane & 15;
    const int m0  = blockIdx.x * 128;
    const int bs0 = blockIdx.x * 32;

    // ---- phase 1: fc1  C[128][256] = flat[m0..+127][160] x iw1t, tanh -> LDS
    for (int p = 0; p < 2; p++) {
        f32x4 acc[4][4];
        #pragma unroll
        for (int mi = 0; mi < 4; mi++)
            #pragma unroll
            for (int ni = 0; ni < 4; ni++) acc[mi][ni] = (f32x4){0.f,0.f,0.f,0.f};
        for (int ks = 0; ks < 5; ks++) {
            const int k = ks * 32 + q * 8;
            f16x8 a[4], b[4];
            #pragma unroll
            for (int mi = 0; mi < 4; mi++)
                a[mi] = *(const f16x8*)&flat[(size_t)(m0 + p*64 + mi*16 + ml) * 160 + k];
            #pragma unroll
            for (int ni = 0; ni < 4; ni++)
                b[ni] = *(const f16x8*)&iw1t[(size_t)(w*64 + ni*16 + ml) * 160 + k];
            #pragma unroll
            for (int mi = 0; mi < 4; mi++)
                #pragma unroll
                for (int ni = 0; ni < 4; ni++)
                    acc[mi][ni] = __builtin_amdgcn_mfma_f32_16x16x32_f16(a[mi], b[ni], acc[mi][ni], 0, 0, 0);
        }
        #pragma unroll
        for (int mi = 0; mi < 4; mi++)
            #pragma unroll
            for (int ni = 0; ni < 4; ni++)
                #pragma unroll
                for (int r = 0; r < 4; r++) {
                    const int row = p*64 + mi*16 + q*4 + r;   // 0..127 block-local
                    const int col = w*64 + ni*16 + ml;        // 0..255
                    const int bs_l = row >> 2, h = row & 3;
                    h1l[bs_l][h*256 + col] = (_Float16)tanh_fast(acc[mi][ni][r] + ib1[col]);
                }
    }
    __syncthreads();

    // ---- phase 2: fc2  [32][64] = h1l[32][1024] x iw2t, k-split 4 waves
    f32x4 a2[2][4];
    #pragma unroll
    for (int mi = 0; mi < 2; mi++)
        #pragma unroll
        for (int ni = 0; ni < 4; ni++) a2[mi][ni] = (f32x4){0.f,0.f,0.f,0.f};
    for (int ks = 0; ks < 8; ks++) {
        const int k = w * 256 + ks * 32 + q * 8;
        f16x8 a[2], b[4];
        #pragma unroll
        for (int mi = 0; mi < 2; mi++)
            a[mi] = *(const f16x8*)&h1l[mi*16 + ml][k];
        #pragma unroll
        for (int ni = 0; ni < 4; ni++)
            b[ni] = *(const f16x8*)&iw2t[(size_t)(ni*16 + ml) * 1024 + k];
        #pragma unroll
        for (int mi = 0; mi < 2; mi++)
            #pragma unroll
            for (int ni = 0; ni < 4; ni++)
                a2[mi][ni] = __builtin_amdgcn_mfma_f32_16x16x32_f16(a[mi], b[ni], a2[mi][ni], 0, 0, 0);
    }
    __syncthreads();   // all h1l reads done before overlay write
    #pragma unroll
    for (int mi = 0; mi < 2; mi++)
        #pragma unroll
        for (int ni = 0; ni < 4; ni++)
            #pragma unroll
            for (int r = 0; r < 4; r++) {
                const int row = mi*16 + q*4 + r;   // 0..31
                const int col = ni*16 + ml;        // 0..63
                red[(size_t)w*2048 + row*64 + col] = a2[mi][ni][r];
            }
    __syncthreads();
    for (int i = t; i < 2048; i += 256) {
        const int row = i >> 6, col = i & 63;
        float s = red[i] + red[2048 + i] + red[4096 + i] + red[6144 + i] + ib2[col];
        seq[(size_t)(bs0 + row) * 64 + col] = s;
    }
}

// ---------------- K3: outer attention (fp32), writes ctxo f16 ---------------
__device__ inline void proj30x64(const float (*sl)[64], const float* __restrict__ w,
                                 float bias, int d, int g, float (*outl)[64])
{
    float acc[8];
    #pragma unroll
    for (int i = 0; i < 8; i++) acc[i] = bias;
    for (int dd = 0; dd < 64; dd += 4) {
        const float w0 = w[(dd+0)*64 + d];
        const float w1 = w[(dd+1)*64 + d];
        const float w2 = w[(dd+2)*64 + d];
        const float w3 = w[(dd+3)*64 + d];
        #pragma unroll
        for (int i = 0; i < 8; i++) {
            const int p = g + i * 4;
            if (p < 30) {
                const float4 s4 = *(const float4*)&sl[p][dd];
                acc[i] += s4.x*w0 + s4.y*w1 + s4.z*w2 + s4.w*w3;
            }
        }
    }
    #pragma unroll
    for (int i = 0; i < 8; i++) { const int p = g + i * 4; if (p < 30) outl[p][d] = acc[i]; }
}

__global__ __launch_bounds__(256) void k_outer_attn(
    const float* __restrict__ seq,
    const float* __restrict__ owq, const float* __restrict__ obq,
    const float* __restrict__ owk, const float* __restrict__ obk,
    const float* __restrict__ owv, const float* __restrict__ obv,
    _Float16* __restrict__ ctxo)
{
    __shared__ float sl[30][64];
    __shared__ float ql[30][64];
    __shared__ float kl[30][64];
    __shared__ float vl[30][64];
    __shared__ float al[30][30];
    const int bh = blockIdx.x, b = bh >> 2, h = bh & 3;
    const int t = threadIdx.x;
    const float* sb = seq + (size_t)b * 1920;
    for (int i = t; i < 1920; i += 256) ((float*)sl)[i] = sb[i];
    __syncthreads();
    const int d = t & 63, g = t >> 6;
    proj30x64(sl, owq + h*4096, obq[h*64 + d], d, g, ql);
    proj30x64(sl, owk + h*4096, obk[h*64 + d], d, g, kl);
    proj30x64(sl, owv + h*4096, obv[h*64 + d], d, g, vl);
    __syncthreads();
    for (int idx = t; idx < 900; idx += 256) {
        const int p = idx / 30, qq = idx - p * 30;
        float s = 0.f;
        for (int dd = 0; dd < 64; dd += 4) {
            const float4 a4 = *(const float4*)&ql[p][dd];
            const float4 b4 = *(const float4*)&kl[qq][dd];
            s += a4.x*b4.x + a4.y*b4.y + a4.z*b4.z + a4.w*b4.w;
        }
        al[p][qq] = s * 0.125f;
    }
    __syncthreads();
    if (t < 30) {
        float mx = -1e30f;
        for (int qq = 0; qq < 30; qq++) mx = fmaxf(mx, al[t][qq]);
        float sum = 0.f;
        for (int qq = 0; qq < 30; qq++) { float e = __expf(al[t][qq] - mx); al[t][qq] = e; sum += e; }
        const float inv = 1.0f / sum;
        for (int qq = 0; qq < 30; qq++) al[t][qq] *= inv;
    }
    __syncthreads();
    _Float16* co = ctxo + (size_t)bh * 1920;
    for (int idx = t; idx < 1920; idx += 256) {
        const int p = idx >> 6, dd = idx & 63;
        float acc = 0.f;
        #pragma unroll
        for (int qq = 0; qq < 30; qq++) acc += al[p][qq] * vl[qq][dd];
        co[idx] = (_Float16)acc;
    }
}

// ---------------- G3: outer fc1  [4096][1024] = ctxo x ow1t, tanh -> f16 ----
// block 256 thr = 2x2 waves of 64x64; tile 128x128; grid 32m x 8n = 256
__global__ __launch_bounds__(256) void k_outer_fc1_mfma(
    const _Float16* __restrict__ ctxo,   // [4096][1920]
    const _Float16* __restrict__ ow1t,   // [1024][1920]
    const float* __restrict__ ob1,
    _Float16* __restrict__ hout)         // [4096][1024] rows=b*4+h
{
    const int t = threadIdx.x, lane = t & 63, w = t >> 6;
    const int q = lane >> 4, ml = lane & 15;
    const int M0 = (blockIdx.x >> 3) * 128 + (w >> 1) * 64;
    const int N0 = (blockIdx.x & 7) * 128 + (w & 1) * 64;
    f32x4 acc[4][4];
    #pragma unroll
    for (int mi = 0; mi < 4; mi++)
        #pragma unroll
        for (int ni = 0; ni < 4; ni++) acc[mi][ni] = (f32x4){0.f,0.f,0.f,0.f};
    for (int ks = 0; ks < 60; ks++) {
        const int k = ks * 32 + q * 8;
        f16x8 a[4], b[4];
        #pragma unroll
        for (int mi = 0; mi < 4; mi++)
            a[mi] = *(const f16x8*)&ctxo[(size_t)(M0 + mi*16 + ml) * 1920 + k];
        #pragma unroll
        for (int ni = 0; ni < 4; ni++)
            b[ni] = *(const f16x8*)&ow1t[(size_t)(N0 + ni*16 + ml) * 1920 + k];
        #pragma unroll
        for (int mi = 0; mi < 4; mi++)
            #pragma unroll
            for (int ni = 0; ni < 4; ni++)
                acc[mi][ni] = __builtin_amdgcn_mfma_f32_16x16x32_f16(a[mi], b[ni], acc[mi][ni], 0, 0, 0);
    }
    #pragma unroll
    for (int mi = 0; mi < 4; mi++)
        #pragma unroll
        for (int ni = 0; ni < 4; ni++) {
            const int col = N0 + ni*16 + ml;
            const float bias = ob1[col];
            #pragma unroll
            for (int r = 0; r < 4; r++) {
                const int row = M0 + mi*16 + q*4 + r;
                hout[(size_t)row * 1024 + col] = (_Float16)tanh_fast(acc[mi][ni][r] + bias);
            }
        }
}

// ---------------- G4: outer fc2  [1024][1080] = hout x ow2t + ob2 -----------
// block 256 thr = 4 waves k-split (1024 each); tile 64x64; grid 16m x 17n
__global__ __launch_bounds__(256) void k_outer_fc2_mfma(
    const _Float16* __restrict__ hout,   // [1024][4096]
    const _Float16* __restrict__ ow2t,   // [1088][4096]
    const float* __restrict__ ob2,
    float* __restrict__ out)             // [1024][1080]
{
    __shared__ float red[4][64][64];     // 64 KB
    const int t = threadIdx.x, lane = t & 63, w = t >> 6;
    const int q = lane >> 4, ml = lane & 15;
    const int M0 = (blockIdx.x / 17) * 64;
    const int N0 = (blockIdx.x % 17) * 64;
    f32x4 acc[4][4];
    #pragma unroll
    for (int mi = 0; mi < 4; mi++)
        #pragma unroll
        for (int ni = 0; ni < 4; ni++) acc[mi][ni] = (f32x4){0.f,0.f,0.f,0.f};
    for (int ks = 0; ks < 32; ks++) {
        const int k = w * 1024 + ks * 32 + q * 8;
        f16x8 a[4], b[4];
        #pragma unroll
        for (int mi = 0; mi < 4; mi++)
            a[mi] = *(const f16x8*)&hout[(size_t)(M0 + mi*16 + ml) * 4096 + k];
        #pragma unroll
        for (int ni = 0; ni < 4; ni++)
            b[ni] = *(const f16x8*)&ow2t[(size_t)(N0 + ni*16 + ml) * 4096 + k];
        #pragma unroll
        for (int mi = 0; mi < 4; mi++)
            #pragma unroll
            for (int ni = 0; ni < 4; ni++)
                acc[mi][ni] = __builtin_amdgcn_mfma_f32_16x16x32_f16(a[mi], b[ni], acc[mi][ni], 0, 0, 0);
    }
    #pragma unroll
    for (int mi = 0; mi < 4; mi++)
        #pragma unroll
        for (int ni = 0; ni < 4; ni++)
            #pragma unroll
            for (int r = 0; r < 4; r++)
                red[w][mi*16 + q*4 + r][ni*16 + ml] = acc[mi][ni][r];
    __syncthreads();
    for (int i = t; i < 4096; i += 256) {
        const int row = i >> 6, col = i & 63;
        const int n = N0 + col;
        if (n < 1080) {
            float s = red[0][row][col] + red[1][row][col] + red[2][row][col] + red[3][row][col] + ob2[n];
            out[(size_t)(M0 + row) * 1080 + n] = s;
        }
    }
}

extern "C" void kernel_launch(void* const* d_in, const int* in_sizes, int n_in,
                              void* d_out, int out_size, void* d_ws, size_t ws_size,
                              hipStream_t stream) {
    const float* x   = (const float*)d_in[0];
    const float* iwq = (const float*)d_in[1];
    const float* ibq = (const float*)d_in[2];
    const float* iwk = (const float*)d_in[3];
    const float* ibk = (const float*)d_in[4];
    const float* iwv = (const float*)d_in[5];
    const float* ibv = (const float*)d_in[6];
    const float* iw1 = (const float*)d_in[7];
    const float* ib1 = (const float*)d_in[8];
    const float* iw2 = (const float*)d_in[9];
    const float* ib2 = (const float*)d_in[10];
    const float* owq = (const float*)d_in[11];
    const float* obq = (const float*)d_in[12];
    const float* owk = (const float*)d_in[13];
    const float* obk = (const float*)d_in[14];
    const float* owv = (const float*)d_in[15];
    const float* obv = (const float*)d_in[16];
    const float* ow1 = (const float*)d_in[17];
    const float* ob1 = (const float*)d_in[18];
    const float* ow2 = (const float*)d_in[19];
    const float* ob2 = (const float*)d_in[20];

    char* ws = (char*)d_ws;
    _Float16* iw1t   = (_Float16*)(ws + 0);          // [256][160]
    _Float16* iw2t   = (_Float16*)(ws + 163840);     // [64][1024]
    _Float16* ow1t   = (_Float16*)(ws + 294912);     // [1024][1920]
    _Float16* ow2t   = (_Float16*)(ws + 4227072);    // [1088][4096]
    _Float16* flat   = (_Float16*)(ws + 13139968);   // [122880][160]
    float*    seq    = (float*)   (ws + 52461568);   // [30720][64]
    _Float16* ctxo   = (_Float16*)(ws + 13139968);   // [4096][1920]  (reuse)
    _Float16* houtb  = (_Float16*)(ws + 28868608);   // [1024][4096]  (reuse)
    float*    out    = (float*)d_out;

    k_tcast<<<dim3((40960   + 255) / 256), dim3(256), 0, stream>>>(iw1, iw1t, 136, 256, 160, 256);
    k_tcast<<<dim3((65536   + 255) / 256), dim3(256), 0, stream>>>(iw2, iw2t, 1024, 64, 1024, 64);
    k_tcast<<<dim3((1966080 + 255) / 256), dim3(256), 0, stream>>>(ow1, ow1t, 1920, 1024, 1920, 1024);
    k_tcast<<<dim3((4456448 + 255) / 256), dim3(256), 0, stream>>>(ow2, ow2t, 4096, 1080, 4096, 1088);

    k_inner_attn    <<<dim3(30720), dim3(64),  0, stream>>>(x, iwq, ibq, iwk, ibk, iwv, ibv, flat);
    k_inner_ml_mfma <<<dim3(960),   dim3(256), 0, stream>>>(flat, iw1t, iw2t, ib1, ib2, seq);
    k_outer_attn    <<<dim3(4096),  dim3(256), 0, stream>>>(seq, owq, obq, owk, obk, owv, obv, ctxo);
    k_outer_fc1_mfma<<<dim3(256),   dim3(256), 0, stream>>>(ctxo, ow1t, ob1, houtb);
    k_outer_fc2_mfma<<<dim3(272),   dim3(256), 0, stream>>>(houtb, ow2t, ob2, out);
}

// Round 4
// 440.537 us; speedup vs baseline: 5.2669x; 1.4192x over previous
//
#include <hip/hip_runtime.h>

// DoubleAttention: B=1024, S_OUT=30, S_IN=17, D_IN=3, H=4
// inner: dkq=6 dv=8 hid=256 out=64 ; outer: dkq=dv=64 hid=1024 out=1080
//
// Round 4: outer attention rewritten as MFMA (1 block/b, 1 wave/head).
//   MFMA layouts (verified, learn_hip m89/m91/m120):
//     A-frag: lane holds A[m=lane&15][k0 + (lane>>4)*8 + j], j=0..7 (16B load)
//     B-frag: lane holds B[k0 + (lane>>4)*8 + j][n=lane&15]  (load from Wt[n][k], 16B)
//     D:      acc[r] -> D[row=(lane>>4)*4+r][col=lane&15]
//
// ws layout (bytes):
//   iw1t  f16 [256][160]    @ 0           (K 136->160 zero-pad)
//   iw2t  f16 [64][1024]    @ 163,840
//   ow1t  f16 [1024][1920]  @ 294,912
//   ow2t  f16 [1088][4096]  @ 4,227,072   (N 1080->1088 zero-pad)
//   flat  f16 [122880][160] @ 13,139,968  (dead after inner_ml; reused)
//   seq   f32 [30720][64]   @ 52,461,568
//   owqt  f16 [4][64][64]   @ 60,325,888
//   owkt  f16 [4][64][64]   @ 60,358,656
//   owvt  f16 [4][64][64]   @ 60,391,424
//   ctxo  f16 [4096][1920]  @ 13,139,968  (reuse)
//   hout  f16 [1024][4096]  @ 28,868,608  (reuse)
// peak = 60.4 MB (<= 74.7 MB proven available)

typedef _Float16 f16x8 __attribute__((ext_vector_type(8)));
typedef float    f32x4 __attribute__((ext_vector_type(4)));

__device__ inline float tanh_fast(float x) {
    float ax = fabsf(x);
    float e  = __expf(2.0f * ax);
    float r  = 1.0f - 2.0f / (e + 1.0f);
    return copysignf(r, x);
}

// ---------------- weight transpose+cast: W[K][N] f32 -> Wt[Npad][Kpad] f16 ---
__global__ __launch_bounds__(256) void k_tcast(
    const float* __restrict__ W, _Float16* __restrict__ Wt,
    int K, int N, int Kpad, int Npad)
{
    int idx = blockIdx.x * 256 + threadIdx.x;
    if (idx >= Npad * Kpad) return;
    int n = idx / Kpad, k = idx - n * Kpad;
    float v = (k < K && n < N) ? W[k * N + n] : 0.0f;
    Wt[idx] = (_Float16)v;
}

// batched for [H][64][64] -> [H][64][64] transposed per head
__global__ __launch_bounds__(256) void k_tcast_h(
    const float* __restrict__ W, _Float16* __restrict__ Wt)
{
    const int h = blockIdx.y;
    const int idx = blockIdx.x * 256 + threadIdx.x;   // 0..4095
    const int n = idx >> 6, k = idx & 63;
    Wt[h * 4096 + n * 64 + k] = (_Float16)W[h * 4096 + k * 64 + n];
}

// ---------------- K1: inner attention -> flat f16 [bs*4+h][160] (zero-pad) --
__global__ __launch_bounds__(64) void k_inner_attn(
    const float* __restrict__ x,
    const float* __restrict__ iwq, const float* __restrict__ ibq,
    const float* __restrict__ iwk, const float* __restrict__ ibk,
    const float* __restrict__ iwv, const float* __restrict__ ibv,
    _Float16* __restrict__ flat_out)
{
    __shared__ float xl[51];
    __shared__ float ql[4][17][6];
    __shared__ float kl[4][17][6];
    __shared__ float vl[4][17][8];
    __shared__ float al[4][17][17];
    const int bs = blockIdx.x;
    const int t  = threadIdx.x;
    if (t < 51) xl[t] = x[bs * 51 + t];
    __syncthreads();
    for (int idx = t; idx < 68; idx += 64) {
        const int h = idx / 17, p = idx % 17;
        const float x0 = xl[p*3+0], x1 = xl[p*3+1], x2 = xl[p*3+2];
        #pragma unroll
        for (int d = 0; d < 6; d++) {
            ql[h][p][d] = ibq[h*6+d] + x0*iwq[(h*3+0)*6+d] + x1*iwq[(h*3+1)*6+d] + x2*iwq[(h*3+2)*6+d];
            kl[h][p][d] = ibk[h*6+d] + x0*iwk[(h*3+0)*6+d] + x1*iwk[(h*3+1)*6+d] + x2*iwk[(h*3+2)*6+d];
        }
        #pragma unroll
        for (int d = 0; d < 8; d++)
            vl[h][p][d] = ibv[h*8+d] + x0*iwv[(h*3+0)*8+d] + x1*iwv[(h*3+1)*8+d] + x2*iwv[(h*3+2)*8+d];
    }
    __syncthreads();
    for (int idx = t; idx < 68; idx += 64) {
        const int h = idx / 17, p = idx % 17;
        float sc[17];
        float mx = -1e30f;
        #pragma unroll
        for (int j = 0; j < 17; j++) {
            float s = 0.f;
            #pragma unroll
            for (int d = 0; d < 6; d++) s += ql[h][p][d] * kl[h][j][d];
            s *= 0.40824829046386307f;
            sc[j] = s; mx = fmaxf(mx, s);
        }
        float sum = 0.f;
        #pragma unroll
        for (int j = 0; j < 17; j++) { float e = __expf(sc[j] - mx); sc[j] = e; sum += e; }
        const float inv = 1.0f / sum;
        #pragma unroll
        for (int j = 0; j < 17; j++) al[h][p][j] = sc[j] * inv;
    }
    __syncthreads();
    _Float16* fo = flat_out + (size_t)bs * 640;
    for (int idx = t; idx < 640; idx += 64) {
        const int h = idx / 160, r = idx - h * 160;
        float acc = 0.f;
        if (r < 136) {
            const int p = r >> 3, dv = r & 7;
            #pragma unroll
            for (int j = 0; j < 17; j++) acc += al[h][p][j] * vl[h][j][dv];
        }
        fo[idx] = (_Float16)acc;
    }
}

// ---------------- G12: inner ML fused (fc1+tanh -> LDS -> fc2), MFMA --------
__global__ __launch_bounds__(256) void k_inner_ml_mfma(
    const _Float16* __restrict__ flat,   // [122880][160]
    const _Float16* __restrict__ iw1t,   // [256][160]
    const _Float16* __restrict__ iw2t,   // [64][1024]
    const float* __restrict__ ib1, const float* __restrict__ ib2,
    float* __restrict__ seq)             // [30720][64]
{
    __shared__ __align__(16) _Float16 h1l[32][1032];
    float* red = (float*)&h1l[0][0];
    const int t = threadIdx.x, lane = t & 63, w = t >> 6;
    const int q = lane >> 4, ml = lane & 15;
    const int m0  = blockIdx.x * 128;
    const int bs0 = blockIdx.x * 32;

    for (int p = 0; p < 2; p++) {
        f32x4 acc[4][4];
        #pragma unroll
        for (int mi = 0; mi < 4; mi++)
            #pragma unroll
            for (int ni = 0; ni < 4; ni++) acc[mi][ni] = (f32x4){0.f,0.f,0.f,0.f};
        for (int ks = 0; ks < 5; ks++) {
            const int k = ks * 32 + q * 8;
            f16x8 a[4], b[4];
            #pragma unroll
            for (int mi = 0; mi < 4; mi++)
                a[mi] = *(const f16x8*)&flat[(size_t)(m0 + p*64 + mi*16 + ml) * 160 + k];
            #pragma unroll
            for (int ni = 0; ni < 4; ni++)
                b[ni] = *(const f16x8*)&iw1t[(size_t)(w*64 + ni*16 + ml) * 160 + k];
            #pragma unroll
            for (int mi = 0; mi < 4; mi++)
                #pragma unroll
                for (int ni = 0; ni < 4; ni++)
                    acc[mi][ni] = __builtin_amdgcn_mfma_f32_16x16x32_f16(a[mi], b[ni], acc[mi][ni], 0, 0, 0);
        }
        #pragma unroll
        for (int mi = 0; mi < 4; mi++)
            #pragma unroll
            for (int ni = 0; ni < 4; ni++)
                #pragma unroll
                for (int r = 0; r < 4; r++) {
                    const int row = p*64 + mi*16 + q*4 + r;
                    const int col = w*64 + ni*16 + ml;
                    const int bs_l = row >> 2, h = row & 3;
                    h1l[bs_l][h*256 + col] = (_Float16)tanh_fast(acc[mi][ni][r] + ib1[col]);
                }
    }
    __syncthreads();

    f32x4 a2[2][4];
    #pragma unroll
    for (int mi = 0; mi < 2; mi++)
        #pragma unroll
        for (int ni = 0; ni < 4; ni++) a2[mi][ni] = (f32x4){0.f,0.f,0.f,0.f};
    for (int ks = 0; ks < 8; ks++) {
        const int k = w * 256 + ks * 32 + q * 8;
        f16x8 a[2], b[4];
        #pragma unroll
        for (int mi = 0; mi < 2; mi++)
            a[mi] = *(const f16x8*)&h1l[mi*16 + ml][k];
        #pragma unroll
        for (int ni = 0; ni < 4; ni++)
            b[ni] = *(const f16x8*)&iw2t[(size_t)(ni*16 + ml) * 1024 + k];
        #pragma unroll
        for (int mi = 0; mi < 2; mi++)
            #pragma unroll
            for (int ni = 0; ni < 4; ni++)
                a2[mi][ni] = __builtin_amdgcn_mfma_f32_16x16x32_f16(a[mi], b[ni], a2[mi][ni], 0, 0, 0);
    }
    __syncthreads();
    #pragma unroll
    for (int mi = 0; mi < 2; mi++)
        #pragma unroll
        for (int ni = 0; ni < 4; ni++)
            #pragma unroll
            for (int r = 0; r < 4; r++) {
                const int row = mi*16 + q*4 + r;
                const int col = ni*16 + ml;
                red[(size_t)w*2048 + row*64 + col] = a2[mi][ni][r];
            }
    __syncthreads();
    for (int i = t; i < 2048; i += 256) {
        const int row = i >> 6, col = i & 63;
        float s = red[i] + red[2048 + i] + red[4096 + i] + red[6144 + i] + ib2[col];
        seq[(size_t)(bs0 + row) * 64 + col] = s;
    }
}

// ---------------- K3: outer attention, MFMA, 1 block/b, 1 wave/head ---------
__device__ inline void oa_proj_rows(
    const _Float16 (*seqf)[72], const _Float16* __restrict__ wt,
    const float* __restrict__ bias, _Float16 (*dst)[72], int q, int ml)
{
    f32x4 acc[2][4];
    #pragma unroll
    for (int mi = 0; mi < 2; mi++)
        #pragma unroll
        for (int ni = 0; ni < 4; ni++) acc[mi][ni] = (f32x4){0.f,0.f,0.f,0.f};
    #pragma unroll
    for (int k0 = 0; k0 < 64; k0 += 32) {
        f16x8 a[2], bb[4];
        #pragma unroll
        for (int mi = 0; mi < 2; mi++) a[mi] = *(const f16x8*)&seqf[mi*16 + ml][k0 + q*8];
        #pragma unroll
        for (int ni = 0; ni < 4; ni++) bb[ni] = *(const f16x8*)&wt[(size_t)(ni*16 + ml)*64 + k0 + q*8];
        #pragma unroll
        for (int mi = 0; mi < 2; mi++)
            #pragma unroll
            for (int ni = 0; ni < 4; ni++)
                acc[mi][ni] = __builtin_amdgcn_mfma_f32_16x16x32_f16(a[mi], bb[ni], acc[mi][ni], 0, 0, 0);
    }
    #pragma unroll
    for (int ni = 0; ni < 4; ni++) {
        const float bi = bias[ni*16 + ml];
        #pragma unroll
        for (int mi = 0; mi < 2; mi++)
            #pragma unroll
            for (int r = 0; r < 4; r++)
                dst[mi*16 + q*4 + r][ni*16 + ml] = (_Float16)(acc[mi][ni][r] + bi);
    }
}

__device__ inline void oa_proj_t(
    const _Float16 (*seqf)[72], const _Float16* __restrict__ wt,
    const float* __restrict__ bias, _Float16 (*dstT)[40], int q, int ml)
{
    f32x4 acc[2][4];
    #pragma unroll
    for (int mi = 0; mi < 2; mi++)
        #pragma unroll
        for (int ni = 0; ni < 4; ni++) acc[mi][ni] = (f32x4){0.f,0.f,0.f,0.f};
    #pragma unroll
    for (int k0 = 0; k0 < 64; k0 += 32) {
        f16x8 a[2], bb[4];
        #pragma unroll
        for (int mi = 0; mi < 2; mi++) a[mi] = *(const f16x8*)&seqf[mi*16 + ml][k0 + q*8];
        #pragma unroll
        for (int ni = 0; ni < 4; ni++) bb[ni] = *(const f16x8*)&wt[(size_t)(ni*16 + ml)*64 + k0 + q*8];
        #pragma unroll
        for (int mi = 0; mi < 2; mi++)
            #pragma unroll
            for (int ni = 0; ni < 4; ni++)
                acc[mi][ni] = __builtin_amdgcn_mfma_f32_16x16x32_f16(a[mi], bb[ni], acc[mi][ni], 0, 0, 0);
    }
    #pragma unroll
    for (int ni = 0; ni < 4; ni++) {
        const float bi = bias[ni*16 + ml];
        #pragma unroll
        for (int mi = 0; mi < 2; mi++)
            #pragma unroll
            for (int r = 0; r < 4; r++)
                dstT[ni*16 + ml][mi*16 + q*4 + r] = (_Float16)(acc[mi][ni][r] + bi);  // transposed
    }
}

__global__ __launch_bounds__(256) void k_outer_attn_mfma(
    const float* __restrict__ seq,       // [1024][30][64] f32
    const _Float16* __restrict__ owqt,   // [4][64][64] (n,k)
    const _Float16* __restrict__ owkt,
    const _Float16* __restrict__ owvt,
    const float* __restrict__ obq, const float* __restrict__ obk,
    const float* __restrict__ obv,
    _Float16* __restrict__ ctxo)         // [4096][1920] rows = b*4+h
{
    __shared__ __align__(16) _Float16 seqf[32][72];
    __shared__ __align__(16) _Float16 qf[4][32][72];
    __shared__ __align__(16) _Float16 kf[4][32][72];
    __shared__ __align__(16) _Float16 vt[4][64][40];
    __shared__ __align__(16) _Float16 pf[4][32][40];
    const int t = threadIdx.x, lane = t & 63, w = t >> 6;   // w = head
    const int q = lane >> 4, ml = lane & 15;
    const int b = blockIdx.x;

    const float* sb = seq + (size_t)b * 1920;
    for (int i = t; i < 2048; i += 256) {
        const int row = i >> 6, col = i & 63;
        seqf[row][col] = (_Float16)(row < 30 ? sb[row*64 + col] : 0.0f);
    }
    __syncthreads();

    oa_proj_rows(seqf, owqt + w*4096, obq + w*64, qf[w], q, ml);
    oa_proj_rows(seqf, owkt + w*4096, obk + w*64, kf[w], q, ml);
    oa_proj_t   (seqf, owvt + w*4096, obv + w*64, vt[w], q, ml);
    __syncthreads();

    // scores S[32][32] = Q x K^T, K=64
    f32x4 sc[2][2];
    #pragma unroll
    for (int mi = 0; mi < 2; mi++)
        #pragma unroll
        for (int ni = 0; ni < 2; ni++) sc[mi][ni] = (f32x4){0.f,0.f,0.f,0.f};
    #pragma unroll
    for (int k0 = 0; k0 < 64; k0 += 32) {
        f16x8 aq[2], bk[2];
        #pragma unroll
        for (int mi = 0; mi < 2; mi++) aq[mi] = *(const f16x8*)&qf[w][mi*16 + ml][k0 + q*8];
        #pragma unroll
        for (int ni = 0; ni < 2; ni++) bk[ni] = *(const f16x8*)&kf[w][ni*16 + ml][k0 + q*8];
        #pragma unroll
        for (int mi = 0; mi < 2; mi++)
            #pragma unroll
            for (int ni = 0; ni < 2; ni++)
                sc[mi][ni] = __builtin_amdgcn_mfma_f32_16x16x32_f16(aq[mi], bk[ni], sc[mi][ni], 0, 0, 0);
    }

    // softmax over cols (j<30 valid), rows = mi*16+q*4+r, cols = ni*16+ml
    const bool maskhi = (ml >= 14);     // col 16+ml >= 30
    #pragma unroll
    for (int mi = 0; mi < 2; mi++) {
        #pragma unroll
        for (int r = 0; r < 4; r++) {
            const float s0 = sc[mi][0][r] * 0.125f;
            const float s1 = maskhi ? -1e30f : sc[mi][1][r] * 0.125f;
            float mx = fmaxf(s0, s1);
            #pragma unroll
            for (int off = 1; off < 16; off <<= 1) mx = fmaxf(mx, __shfl_xor(mx, off, 64));
            const float e0 = __expf(s0 - mx);
            const float e1 = __expf(s1 - mx);   // masked -> exp(-huge) = 0
            float sm = e0 + e1;
            #pragma unroll
            for (int off = 1; off < 16; off <<= 1) sm += __shfl_xor(sm, off, 64);
            const float inv = 1.0f / sm;
            pf[w][mi*16 + q*4 + r][ml]      = (_Float16)(e0 * inv);
            pf[w][mi*16 + q*4 + r][16 + ml] = (_Float16)(e1 * inv);
        }
    }
    __syncthreads();

    // ctx[32][64] = P[32][32] x V[32][64]  (K=32, single k-step)
    f16x8 ap[2], bv[4];
    #pragma unroll
    for (int mi = 0; mi < 2; mi++) ap[mi] = *(const f16x8*)&pf[w][mi*16 + ml][q*8];
    #pragma unroll
    for (int ni = 0; ni < 4; ni++) bv[ni] = *(const f16x8*)&vt[w][ni*16 + ml][q*8];
    f32x4 oa[2][4];
    #pragma unroll
    for (int mi = 0; mi < 2; mi++)
        #pragma unroll
        for (int ni = 0; ni < 4; ni++) {
            oa[mi][ni] = (f32x4){0.f,0.f,0.f,0.f};
            oa[mi][ni] = __builtin_amdgcn_mfma_f32_16x16x32_f16(ap[mi], bv[ni], oa[mi][ni], 0, 0, 0);
        }

    _Float16* co = ctxo + (size_t)(b*4 + w) * 1920;
    #pragma unroll
    for (int mi = 0; mi < 2; mi++)
        #pragma unroll
        for (int r = 0; r < 4; r++) {
            const int row = mi*16 + q*4 + r;
            if (row < 30) {
                #pragma unroll
                for (int ni = 0; ni < 4; ni++)
                    co[row*64 + ni*16 + ml] = (_Float16)oa[mi][ni][r];
            }
        }
}

// ---------------- G3: outer fc1  [4096][1024] = ctxo x ow1t, tanh -> f16 ----
__global__ __launch_bounds__(256) void k_outer_fc1_mfma(
    const _Float16* __restrict__ ctxo,   // [4096][1920]
    const _Float16* __restrict__ ow1t,   // [1024][1920]
    const float* __restrict__ ob1,
    _Float16* __restrict__ hout)         // [4096][1024]
{
    const int t = threadIdx.x, lane = t & 63, w = t >> 6;
    const int q = lane >> 4, ml = lane & 15;
    const int M0 = (blockIdx.x >> 3) * 128 + (w >> 1) * 64;
    const int N0 = (blockIdx.x & 7) * 128 + (w & 1) * 64;
    f32x4 acc[4][4];
    #pragma unroll
    for (int mi = 0; mi < 4; mi++)
        #pragma unroll
        for (int ni = 0; ni < 4; ni++) acc[mi][ni] = (f32x4){0.f,0.f,0.f,0.f};
    for (int ks = 0; ks < 60; ks++) {
        const int k = ks * 32 + q * 8;
        f16x8 a[4], b[4];
        #pragma unroll
        for (int mi = 0; mi < 4; mi++)
            a[mi] = *(const f16x8*)&ctxo[(size_t)(M0 + mi*16 + ml) * 1920 + k];
        #pragma unroll
        for (int ni = 0; ni < 4; ni++)
            b[ni] = *(const f16x8*)&ow1t[(size_t)(N0 + ni*16 + ml) * 1920 + k];
        #pragma unroll
        for (int mi = 0; mi < 4; mi++)
            #pragma unroll
            for (int ni = 0; ni < 4; ni++)
                acc[mi][ni] = __builtin_amdgcn_mfma_f32_16x16x32_f16(a[mi], b[ni], acc[mi][ni], 0, 0, 0);
    }
    #pragma unroll
    for (int mi = 0; mi < 4; mi++)
        #pragma unroll
        for (int ni = 0; ni < 4; ni++) {
            const int col = N0 + ni*16 + ml;
            const float bias = ob1[col];
            #pragma unroll
            for (int r = 0; r < 4; r++) {
                const int row = M0 + mi*16 + q*4 + r;
                hout[(size_t)row * 1024 + col] = (_Float16)tanh_fast(acc[mi][ni][r] + bias);
            }
        }
}

// ---------------- G4: outer fc2  [1024][1080] = hout x ow2t + ob2 -----------
__global__ __launch_bounds__(256) void k_outer_fc2_mfma(
    const _Float16* __restrict__ hout,   // [1024][4096]
    const _Float16* __restrict__ ow2t,   // [1088][4096]
    const float* __restrict__ ob2,
    float* __restrict__ out)             // [1024][1080]
{
    __shared__ float red[4][64][64];
    const int t = threadIdx.x, lane = t & 63, w = t >> 6;
    const int q = lane >> 4, ml = lane & 15;
    const int M0 = (blockIdx.x / 17) * 64;
    const int N0 = (blockIdx.x % 17) * 64;
    f32x4 acc[4][4];
    #pragma unroll
    for (int mi = 0; mi < 4; mi++)
        #pragma unroll
        for (int ni = 0; ni < 4; ni++) acc[mi][ni] = (f32x4){0.f,0.f,0.f,0.f};
    for (int ks = 0; ks < 32; ks++) {
        const int k = w * 1024 + ks * 32 + q * 8;
        f16x8 a[4], b[4];
        #pragma unroll
        for (int mi = 0; mi < 4; mi++)
            a[mi] = *(const f16x8*)&hout[(size_t)(M0 + mi*16 + ml) * 4096 + k];
        #pragma unroll
        for (int ni = 0; ni < 4; ni++)
            b[ni] = *(const f16x8*)&ow2t[(size_t)(N0 + ni*16 + ml) * 4096 + k];
        #pragma unroll
        for (int mi = 0; mi < 4; mi++)
            #pragma unroll
            for (int ni = 0; ni < 4; ni++)
                acc[mi][ni] = __builtin_amdgcn_mfma_f32_16x16x32_f16(a[mi], b[ni], acc[mi][ni], 0, 0, 0);
    }
    #pragma unroll
    for (int mi = 0; mi < 4; mi++)
        #pragma unroll
        for (int ni = 0; ni < 4; ni++)
            #pragma unroll
            for (int r = 0; r < 4; r++)
                red[w][mi*16 + q*4 + r][ni*16 + ml] = acc[mi][ni][r];
    __syncthreads();
    for (int i = t; i < 4096; i += 256) {
        const int row = i >> 6, col = i & 63;
        const int n = N0 + col;
        if (n < 1080) {
            float s = red[0][row][col] + red[1][row][col] + red[2][row][col] + red[3][row][col] + ob2[n];
            out[(size_t)(M0 + row) * 1080 + n] = s;
        }
    }
}

extern "C" void kernel_launch(void* const* d_in, const int* in_sizes, int n_in,
                              void* d_out, int out_size, void* d_ws, size_t ws_size,
                              hipStream_t stream) {
    const float* x   = (const float*)d_in[0];
    const float* iwq = (const float*)d_in[1];
    const float* ibq = (const float*)d_in[2];
    const float* iwk = (const float*)d_in[3];
    const float* ibk = (const float*)d_in[4];
    const float* iwv = (const float*)d_in[5];
    const float* ibv = (const float*)d_in[6];
    const float* iw1 = (const float*)d_in[7];
    const float* ib1 = (const float*)d_in[8];
    const float* iw2 = (const float*)d_in[9];
    const float* ib2 = (const float*)d_in[10];
    const float* owq = (const float*)d_in[11];
    const float* obq = (const float*)d_in[12];
    const float* owk = (const float*)d_in[13];
    const float* obk = (const float*)d_in[14];
    const float* owv = (const float*)d_in[15];
    const float* obv = (const float*)d_in[16];
    const float* ow1 = (const float*)d_in[17];
    const float* ob1 = (const float*)d_in[18];
    const float* ow2 = (const float*)d_in[19];
    const float* ob2 = (const float*)d_in[20];

    char* ws = (char*)d_ws;
    _Float16* iw1t   = (_Float16*)(ws + 0);          // [256][160]
    _Float16* iw2t   = (_Float16*)(ws + 163840);     // [64][1024]
    _Float16* ow1t   = (_Float16*)(ws + 294912);     // [1024][1920]
    _Float16* ow2t   = (_Float16*)(ws + 4227072);    // [1088][4096]
    _Float16* flat   = (_Float16*)(ws + 13139968);   // [122880][160]
    float*    seq    = (float*)   (ws + 52461568);   // [30720][64]
    _Float16* owqt   = (_Float16*)(ws + 60325888);   // [4][64][64]
    _Float16* owkt   = (_Float16*)(ws + 60358656);
    _Float16* owvt   = (_Float16*)(ws + 60391424);
    _Float16* ctxo   = (_Float16*)(ws + 13139968);   // [4096][1920]  (reuse)
    _Float16* houtb  = (_Float16*)(ws + 28868608);   // [1024][4096]  (reuse)
    float*    out    = (float*)d_out;

    k_tcast<<<dim3((40960   + 255) / 256), dim3(256), 0, stream>>>(iw1, iw1t, 136, 256, 160, 256);
    k_tcast<<<dim3((65536   + 255) / 256), dim3(256), 0, stream>>>(iw2, iw2t, 1024, 64, 1024, 64);
    k_tcast<<<dim3((1966080 + 255) / 256), dim3(256), 0, stream>>>(ow1, ow1t, 1920, 1024, 1920, 1024);
    k_tcast<<<dim3((4456448 + 255) / 256), dim3(256), 0, stream>>>(ow2, ow2t, 4096, 1080, 4096, 1088);
    k_tcast_h<<<dim3(16, 4), dim3(256), 0, stream>>>(owq, owqt);
    k_tcast_h<<<dim3(16, 4), dim3(256), 0, stream>>>(owk, owkt);
    k_tcast_h<<<dim3(16, 4), dim3(256), 0, stream>>>(owv, owvt);

    k_inner_attn    <<<dim3(30720), dim3(64),  0, stream>>>(x, iwq, ibq, iwk, ibk, iwv, ibv, flat);
    k_inner_ml_mfma <<<dim3(960),   dim3(256), 0, stream>>>(flat, iw1t, iw2t, ib1, ib2, seq);
    k_outer_attn_mfma<<<dim3(1024), dim3(256), 0, stream>>>(seq, owqt, owkt, owvt, obq, obk, obv, ctxo);
    k_outer_fc1_mfma<<<dim3(256),   dim3(256), 0, stream>>>(ctxo, ow1t, ob1, houtb);
    k_outer_fc2_mfma<<<dim3(272),   dim3(256), 0, stream>>>(houtb, ow2t, ob2, out);
}

// Round 6
// 382.311 us; speedup vs baseline: 6.0690x; 1.1523x over previous
//
#include <hip/hip_runtime.h>

// DoubleAttention: B=1024, S_OUT=30, S_IN=17, D_IN=3, H=4
// Round 6: fix compile error (address-of-vector-element) via union halves.
//
// 32x32x16 frag layouts (extension of verified 16x16x32 pattern; C/D per m74/m101):
//   A: lane holds A[m=lane&31][k=(lane>>5)*8+j], j=0..7
//   B: lane holds B[k=(lane>>5)*8+j][n=lane&31]
//   D: reg r -> D[row=(r&3)+8*(r>>2)+4*(lane>>5)][col=lane&31]
//
// flat k-ordering: k' = dv*20 + p  (p 0..16 valid, 17..19 zero-weighted pad)

typedef _Float16 f16x8 __attribute__((ext_vector_type(8)));
typedef _Float16 f16x4 __attribute__((ext_vector_type(4)));
typedef float    f32x4 __attribute__((ext_vector_type(4)));
typedef float    f32x16 __attribute__((ext_vector_type(16)));

union F16x8u { f16x8 v; f16x4 q[2]; };

__device__ inline float tanh_fast(float x) {
    float ax = fabsf(x);
    float e  = __expf(2.0f * ax);
    float r  = 1.0f - 2.0f / (e + 1.0f);
    return copysignf(r, x);
}

__device__ inline f32x16 zero16() {
    f32x16 z;
    #pragma unroll
    for (int i = 0; i < 16; i++) z[i] = 0.f;
    return z;
}

// ---------- prep: inner QKV weight frag arrays [64][8] (bias in k=3) --------
__global__ __launch_bounds__(256) void k_prep_frags(
    const float* __restrict__ iwq, const float* __restrict__ ibq,
    const float* __restrict__ iwk, const float* __restrict__ ibk,
    const float* __restrict__ iwv, const float* __restrict__ ibv,
    _Float16* __restrict__ wqf, _Float16* __restrict__ wkf, _Float16* __restrict__ wvf)
{
    const float SC = 0.40824829046386307f;   // 1/sqrt(6) folded into Q
    for (int i = threadIdx.x; i < 512; i += 256) {
        const int lanev = i >> 3, jj = i & 7;
        const int n = lanev & 31, grp = lanev >> 5;
        const int h = n >> 3, dk = n & 7;
        float q = 0.f, k = 0.f, v = 0.f;
        if (!grp) {
            if (jj < 3) {
                if (dk < 6) { q = iwq[h*18 + jj*6 + dk] * SC; k = iwk[h*18 + jj*6 + dk]; }
                v = iwv[h*24 + jj*8 + dk];
            } else if (jj == 3) {
                if (dk < 6) { q = ibq[h*6 + dk] * SC; k = ibk[h*6 + dk]; }
                v = ibv[h*8 + dk];
            }
        }
        wqf[i] = (_Float16)q; wkf[i] = (_Float16)k; wvf[i] = (_Float16)v;
    }
}

// ---------- tiled transpose+cast: W[K][N] f32 -> Wt[N][Kpad] f16 ------------
__global__ __launch_bounds__(256) void k_tcastT(
    const float* __restrict__ W, _Float16* __restrict__ Wt,
    int K, int N, int Kpad)
{
    __shared__ _Float16 tile[64][65];
    const int k0 = blockIdx.x * 64, n0 = blockIdx.y * 64;
    for (int i = threadIdx.x; i < 4096; i += 256) {
        const int r = i >> 6, c = i & 63;
        const int k = k0 + r, n = n0 + c;
        float v = (k < K && n < N) ? W[(size_t)k * N + n] : 0.f;
        tile[c][r] = (_Float16)v;
    }
    __syncthreads();
    for (int i = threadIdx.x; i < 4096; i += 256) {
        const int r = i >> 6, c = i & 63;
        Wt[(size_t)(n0 + r) * Kpad + k0 + c] = tile[r][c];
    }
}

// ---------- iw1t builder with k' = dv*20+p ordering, zero pads --------------
__global__ void k_tcast_iw1(const float* __restrict__ iw1, _Float16* __restrict__ iw1t)
{
    const int n = blockIdx.x;          // 0..255
    const int t = threadIdx.x;         // 0..159 = k'
    const int dv = t / 20, p = t % 20;
    float v = (p < 17) ? iw1[(p*8 + dv) * 256 + n] : 0.f;
    iw1t[n * 160 + t] = (_Float16)v;
}

// batched [H][64][64] -> per-head transposed f16
__global__ __launch_bounds__(256) void k_tcast_h(
    const float* __restrict__ W, _Float16* __restrict__ Wt)
{
    const int h = blockIdx.y;
    const int idx = blockIdx.x * 256 + threadIdx.x;
    const int n = idx >> 6, k = idx & 63;
    Wt[h * 4096 + n * 64 + k] = (_Float16)W[h * 4096 + k * 64 + n];
}

// ---------- K1: inner attention, MFMA, 1 wave per (b,s) ---------------------
__global__ __launch_bounds__(256, 3) void k_inner_attn_mfma(
    const float* __restrict__ x,
    const _Float16* __restrict__ wqf, const _Float16* __restrict__ wkf,
    const _Float16* __restrict__ wvf,
    _Float16* __restrict__ flat)
{
    // per-wave LDS region: kq[32][36], qq[32][36], vt[32][36], pf[32][36], fo2[640]
    __shared__ __align__(16) _Float16 lds[4][5248];
    const int t = threadIdx.x, lane = t & 63, w = t >> 6;
    const int l31 = lane & 31, grp = lane >> 5;
    const int bs = blockIdx.x * 4 + w;
    _Float16* kq  = &lds[w][0];
    _Float16* qq  = &lds[w][1152];
    _Float16* vt  = &lds[w][2304];
    _Float16* pf  = &lds[w][3456];
    _Float16* fo2 = &lds[w][4608];

    // X_ext fragment: row j=l31 (grp0), cols {x0,x1,x2,1,0,0,0,0}
    f16x8 xf;
    #pragma unroll
    for (int i = 0; i < 8; i++) xf[i] = (_Float16)0.f;
    if (grp == 0 && l31 < 17) {
        const float* xr = x + (size_t)bs * 51 + l31 * 3;
        xf[0] = (_Float16)xr[0];
        xf[1] = (_Float16)xr[1];
        xf[2] = (_Float16)xr[2];
        xf[3] = (_Float16)1.0f;
    }
    const f16x8 wq8 = *(const f16x8*)&wqf[lane * 8];
    const f16x8 wk8 = *(const f16x8*)&wkf[lane * 8];
    const f16x8 wv8 = *(const f16x8*)&wvf[lane * 8];

    // K^T = Wk_ext^T x X_ext^T  (D: col=j, rows=n) ; same for Q^T ; V = X x Wv
    f32x16 kt = __builtin_amdgcn_mfma_f32_32x32x16_f16(wk8, xf, zero16(), 0, 0, 0);
    f32x16 qt = __builtin_amdgcn_mfma_f32_32x32x16_f16(wq8, xf, zero16(), 0, 0, 0);
    f32x16 vv = __builtin_amdgcn_mfma_f32_32x32x16_f16(xf, wv8, zero16(), 0, 0, 0);

    #pragma unroll
    for (int qd = 0; qd < 4; qd++) {
        const int base = 8 * qd + 4 * grp;
        f16x4 a, b, c;
        #pragma unroll
        for (int i = 0; i < 4; i++) {
            a[i] = (_Float16)kt[4*qd + i];
            b[i] = (_Float16)qt[4*qd + i];
            c[i] = (_Float16)vv[4*qd + i];
        }
        *(f16x4*)&kq[l31 * 36 + base] = a;   // kq[j][n]
        *(f16x4*)&qq[l31 * 36 + base] = b;   // qq[p][n]
        *(f16x4*)&vt[l31 * 36 + base] = c;   // vt[n][j]
    }

    #pragma unroll
    for (int h = 0; h < 4; h++) {
        // ---- scores S^T[j][p], K-dim = dk(6)+zeros, A=K rows j, B=Q cols p
        F16x8u ka, qb;
        #pragma unroll
        for (int i = 0; i < 8; i++) { ka.v[i] = (_Float16)0.f; qb.v[i] = (_Float16)0.f; }
        if (grp == 0) {
            ka.q[0] = *(const f16x4*)&kq[l31 * 36 + h * 8];
            ka.q[1] = *(const f16x4*)&kq[l31 * 36 + h * 8 + 4];
            qb.q[0] = *(const f16x4*)&qq[l31 * 36 + h * 8];
            qb.q[1] = *(const f16x4*)&qq[l31 * 36 + h * 8 + 4];
        }
        f32x16 s = __builtin_amdgcn_mfma_f32_32x32x16_f16(ka.v, qb.v, zero16(), 0, 0, 0);

        // ---- softmax over keys j (rows): in-lane regs + one shfl across halves
        // reg r -> j = (r&3) + 8*(r>>2) + 4*grp ; valid j<17: r<8, or (r==8 && grp==0)
        float mx = -1e30f;
        #pragma unroll
        for (int r = 0; r < 16; r++) {
            const bool val = (r < 8) || (r == 8 && grp == 0);
            if (val) mx = fmaxf(mx, s[r]);
        }
        mx = fmaxf(mx, __shfl_xor(mx, 32));
        float e[16], sum = 0.f;
        #pragma unroll
        for (int r = 0; r < 16; r++) {
            const bool val = (r < 8) || (r == 8 && grp == 0);
            e[r] = val ? __expf(s[r] - mx) : 0.f;
            sum += e[r];
        }
        sum += __shfl_xor(sum, 32);
        const float inv = __builtin_amdgcn_rcpf(sum);
        #pragma unroll
        for (int qd = 0; qd < 4; qd++) {
            f16x4 pk;
            #pragma unroll
            for (int i = 0; i < 4; i++) pk[i] = (_Float16)(e[4*qd + i] * inv);
            *(f16x4*)&pf[l31 * 36 + 8 * qd + 4 * grp] = pk;   // pf[p][j]
        }

        // ---- ctx = P x V : A = pf[q][j], B = vt[h*8+dv][j]
        F16x8u pa1, pa2, vb1, vb2;
        pa1.q[0] = *(const f16x4*)&pf[l31 * 36 + grp * 8];
        pa1.q[1] = *(const f16x4*)&pf[l31 * 36 + grp * 8 + 4];
        pa2.q[0] = *(const f16x4*)&pf[l31 * 36 + 16 + grp * 8];
        pa2.q[1] = *(const f16x4*)&pf[l31 * 36 + 16 + grp * 8 + 4];
        const int vr = (h * 8 + (l31 & 7)) * 36;
        vb1.q[0] = *(const f16x4*)&vt[vr + grp * 8];
        vb1.q[1] = *(const f16x4*)&vt[vr + grp * 8 + 4];
        vb2.q[0] = *(const f16x4*)&vt[vr + 16 + grp * 8];
        vb2.q[1] = *(const f16x4*)&vt[vr + 16 + grp * 8 + 4];
        f32x16 c = __builtin_amdgcn_mfma_f32_32x32x16_f16(pa1.v, vb1.v, zero16(), 0, 0, 0);
        c = __builtin_amdgcn_mfma_f32_32x32x16_f16(pa2.v, vb2.v, c, 0, 0, 0);

        // ---- stage ctx: fo2[h*160 + dv*20 + q], q-quads (skip q>=20)
        if (l31 < 8) {
            #pragma unroll
            for (int qd = 0; qd < 4; qd++) {
                const int jb = 8 * qd + 4 * grp;
                if (jb < 20) {
                    f16x4 ck;
                    #pragma unroll
                    for (int i = 0; i < 4; i++) ck[i] = (_Float16)c[4*qd + i];
                    *(f16x4*)&fo2[h * 160 + l31 * 20 + jb] = ck;
                }
            }
        }
    }

    // ---- coalesced global write: 640 f16 = 1280B
    _Float16* fg = flat + (size_t)bs * 640;
    *(f16x8*)&fg[lane * 8] = *(const f16x8*)&fo2[lane * 8];
    if (lane < 16)
        *(f16x8*)&fg[512 + lane * 8] = *(const f16x8*)&fo2[512 + lane * 8];
}

// ---------- G12: inner ML fused (fc1+tanh -> LDS -> fc2), MFMA --------------
__global__ __launch_bounds__(256) void k_inner_ml_mfma(
    const _Float16* __restrict__ flat,   // [122880][160] (k'=dv*20+p)
    const _Float16* __restrict__ iw1t,   // [256][160]    (same k' order)
    const _Float16* __restrict__ iw2t,   // [64][1024]
    const float* __restrict__ ib1, const float* __restrict__ ib2,
    float* __restrict__ seq)             // [30720][64]
{
    __shared__ __align__(16) _Float16 h1l[32][1032];
    float* red = (float*)&h1l[0][0];
    const int t = threadIdx.x, lane = t & 63, w = t >> 6;
    const int q = lane >> 4, ml = lane & 15;
    const int m0  = blockIdx.x * 128;
    const int bs0 = blockIdx.x * 32;

    for (int p = 0; p < 2; p++) {
        f32x4 acc[4][4];
        #pragma unroll
        for (int mi = 0; mi < 4; mi++)
            #pragma unroll
            for (int ni = 0; ni < 4; ni++) acc[mi][ni] = (f32x4){0.f,0.f,0.f,0.f};
        for (int ks = 0; ks < 5; ks++) {
            const int k = ks * 32 + q * 8;
            f16x8 a[4], b[4];
            #pragma unroll
            for (int mi = 0; mi < 4; mi++)
                a[mi] = *(const f16x8*)&flat[(size_t)(m0 + p*64 + mi*16 + ml) * 160 + k];
            #pragma unroll
            for (int ni = 0; ni < 4; ni++)
                b[ni] = *(const f16x8*)&iw1t[(size_t)(w*64 + ni*16 + ml) * 160 + k];
            #pragma unroll
            for (int mi = 0; mi < 4; mi++)
                #pragma unroll
                for (int ni = 0; ni < 4; ni++)
                    acc[mi][ni] = __builtin_amdgcn_mfma_f32_16x16x32_f16(a[mi], b[ni], acc[mi][ni], 0, 0, 0);
        }
        #pragma unroll
        for (int mi = 0; mi < 4; mi++)
            #pragma unroll
            for (int ni = 0; ni < 4; ni++)
                #pragma unroll
                for (int r = 0; r < 4; r++) {
                    const int row = p*64 + mi*16 + q*4 + r;
                    const int col = w*64 + ni*16 + ml;
                    const int bs_l = row >> 2, h = row & 3;
                    h1l[bs_l][h*256 + col] = (_Float16)tanh_fast(acc[mi][ni][r] + ib1[col]);
                }
    }
    __syncthreads();

    f32x4 a2[2][4];
    #pragma unroll
    for (int mi = 0; mi < 2; mi++)
        #pragma unroll
        for (int ni = 0; ni < 4; ni++) a2[mi][ni] = (f32x4){0.f,0.f,0.f,0.f};
    for (int ks = 0; ks < 8; ks++) {
        const int k = w * 256 + ks * 32 + q * 8;
        f16x8 a[2], b[4];
        #pragma unroll
        for (int mi = 0; mi < 2; mi++)
            a[mi] = *(const f16x8*)&h1l[mi*16 + ml][k];
        #pragma unroll
        for (int ni = 0; ni < 4; ni++)
            b[ni] = *(const f16x8*)&iw2t[(size_t)(ni*16 + ml) * 1024 + k];
        #pragma unroll
        for (int mi = 0; mi < 2; mi++)
            #pragma unroll
            for (int ni = 0; ni < 4; ni++)
                a2[mi][ni] = __builtin_amdgcn_mfma_f32_16x16x32_f16(a[mi], b[ni], a2[mi][ni], 0, 0, 0);
    }
    __syncthreads();
    #pragma unroll
    for (int mi = 0; mi < 2; mi++)
        #pragma unroll
        for (int ni = 0; ni < 4; ni++)
            #pragma unroll
            for (int r = 0; r < 4; r++) {
                const int row = mi*16 + q*4 + r;
                const int col = ni*16 + ml;
                red[(size_t)w*2048 + row*64 + col] = a2[mi][ni][r];
            }
    __syncthreads();
    for (int i = t; i < 2048; i += 256) {
        const int row = i >> 6, col = i & 63;
        float s = red[i] + red[2048 + i] + red[4096 + i] + red[6144 + i] + ib2[col];
        seq[(size_t)(bs0 + row) * 64 + col] = s;
    }
}

// ---------- K3: outer attention, MFMA, 1 block/b, 1 wave/head ---------------
__device__ inline void oa_proj_rows(
    const _Float16 (*seqf)[72], const _Float16* __restrict__ wt,
    const float* __restrict__ bias, _Float16 (*dst)[72], int q, int ml)
{
    f32x4 acc[2][4];
    #pragma unroll
    for (int mi = 0; mi < 2; mi++)
        #pragma unroll
        for (int ni = 0; ni < 4; ni++) acc[mi][ni] = (f32x4){0.f,0.f,0.f,0.f};
    #pragma unroll
    for (int k0 = 0; k0 < 64; k0 += 32) {
        f16x8 a[2], bb[4];
        #pragma unroll
        for (int mi = 0; mi < 2; mi++) a[mi] = *(const f16x8*)&seqf[mi*16 + ml][k0 + q*8];
        #pragma unroll
        for (int ni = 0; ni < 4; ni++) bb[ni] = *(const f16x8*)&wt[(size_t)(ni*16 + ml)*64 + k0 + q*8];
        #pragma unroll
        for (int mi = 0; mi < 2; mi++)
            #pragma unroll
            for (int ni = 0; ni < 4; ni++)
                acc[mi][ni] = __builtin_amdgcn_mfma_f32_16x16x32_f16(a[mi], bb[ni], acc[mi][ni], 0, 0, 0);
    }
    #pragma unroll
    for (int ni = 0; ni < 4; ni++) {
        const float bi = bias[ni*16 + ml];
        #pragma unroll
        for (int mi = 0; mi < 2; mi++)
            #pragma unroll
            for (int r = 0; r < 4; r++)
                dst[mi*16 + q*4 + r][ni*16 + ml] = (_Float16)(acc[mi][ni][r] + bi);
    }
}

__device__ inline void oa_proj_t(
    const _Float16 (*seqf)[72], const _Float16* __restrict__ wt,
    const float* __restrict__ bias, _Float16 (*dstT)[40], int q, int ml)
{
    f32x4 acc[2][4];
    #pragma unroll
    for (int mi = 0; mi < 2; mi++)
        #pragma unroll
        for (int ni = 0; ni < 4; ni++) acc[mi][ni] = (f32x4){0.f,0.f,0.f,0.f};
    #pragma unroll
    for (int k0 = 0; k0 < 64; k0 += 32) {
        f16x8 a[2], bb[4];
        #pragma unroll
        for (int mi = 0; mi < 2; mi++) a[mi] = *(const f16x8*)&seqf[mi*16 + ml][k0 + q*8];
        #pragma unroll
        for (int ni = 0; ni < 4; ni++) bb[ni] = *(const f16x8*)&wt[(size_t)(ni*16 + ml)*64 + k0 + q*8];
        #pragma unroll
        for (int mi = 0; mi < 2; mi++)
            #pragma unroll
            for (int ni = 0; ni < 4; ni++)
                acc[mi][ni] = __builtin_amdgcn_mfma_f32_16x16x32_f16(a[mi], bb[ni], acc[mi][ni], 0, 0, 0);
    }
    #pragma unroll
    for (int ni = 0; ni < 4; ni++) {
        const float bi = bias[ni*16 + ml];
        #pragma unroll
        for (int mi = 0; mi < 2; mi++)
            #pragma unroll
            for (int r = 0; r < 4; r++)
                dstT[ni*16 + ml][mi*16 + q*4 + r] = (_Float16)(acc[mi][ni][r] + bi);
    }
}

__global__ __launch_bounds__(256) void k_outer_attn_mfma(
    const float* __restrict__ seq,
    const _Float16* __restrict__ owqt,
    const _Float16* __restrict__ owkt,
    const _Float16* __restrict__ owvt,
    const float* __restrict__ obq, const float* __restrict__ obk,
    const float* __restrict__ obv,
    _Float16* __restrict__ ctxo)
{
    __shared__ __align__(16) _Float16 seqf[32][72];
    __shared__ __align__(16) _Float16 qf[4][32][72];
    __shared__ __align__(16) _Float16 kf[4][32][72];
    __shared__ __align__(16) _Float16 vt[4][64][40];
    __shared__ __align__(16) _Float16 pf[4][32][40];
    const int t = threadIdx.x, lane = t & 63, w = t >> 6;
    const int q = lane >> 4, ml = lane & 15;
    const int b = blockIdx.x;

    const float* sb = seq + (size_t)b * 1920;
    for (int i = t; i < 2048; i += 256) {
        const int row = i >> 6, col = i & 63;
        seqf[row][col] = (_Float16)(row < 30 ? sb[row*64 + col] : 0.0f);
    }
    __syncthreads();

    oa_proj_rows(seqf, owqt + w*4096, obq + w*64, qf[w], q, ml);
    oa_proj_rows(seqf, owkt + w*4096, obk + w*64, kf[w], q, ml);
    oa_proj_t   (seqf, owvt + w*4096, obv + w*64, vt[w], q, ml);
    __syncthreads();

    f32x4 sc[2][2];
    #pragma unroll
    for (int mi = 0; mi < 2; mi++)
        #pragma unroll
        for (int ni = 0; ni < 2; ni++) sc[mi][ni] = (f32x4){0.f,0.f,0.f,0.f};
    #pragma unroll
    for (int k0 = 0; k0 < 64; k0 += 32) {
        f16x8 aq[2], bk[2];
        #pragma unroll
        for (int mi = 0; mi < 2; mi++) aq[mi] = *(const f16x8*)&qf[w][mi*16 + ml][k0 + q*8];
        #pragma unroll
        for (int ni = 0; ni < 2; ni++) bk[ni] = *(const f16x8*)&kf[w][ni*16 + ml][k0 + q*8];
        #pragma unroll
        for (int mi = 0; mi < 2; mi++)
            #pragma unroll
            for (int ni = 0; ni < 2; ni++)
                sc[mi][ni] = __builtin_amdgcn_mfma_f32_16x16x32_f16(aq[mi], bk[ni], sc[mi][ni], 0, 0, 0);
    }

    const bool maskhi = (ml >= 14);
    #pragma unroll
    for (int mi = 0; mi < 2; mi++) {
        #pragma unroll
        for (int r = 0; r < 4; r++) {
            const float s0 = sc[mi][0][r] * 0.125f;
            const float s1 = maskhi ? -1e30f : sc[mi][1][r] * 0.125f;
            float mx = fmaxf(s0, s1);
            #pragma unroll
            for (int off = 1; off < 16; off <<= 1) mx = fmaxf(mx, __shfl_xor(mx, off, 64));
            const float e0 = __expf(s0 - mx);
            const float e1 = __expf(s1 - mx);
            float sm = e0 + e1;
            #pragma unroll
            for (int off = 1; off < 16; off <<= 1) sm += __shfl_xor(sm, off, 64);
            const float inv = 1.0f / sm;
            pf[w][mi*16 + q*4 + r][ml]      = (_Float16)(e0 * inv);
            pf[w][mi*16 + q*4 + r][16 + ml] = (_Float16)(e1 * inv);
        }
    }
    __syncthreads();

    f16x8 ap[2], bv[4];
    #pragma unroll
    for (int mi = 0; mi < 2; mi++) ap[mi] = *(const f16x8*)&pf[w][mi*16 + ml][q*8];
    #pragma unroll
    for (int ni = 0; ni < 4; ni++) bv[ni] = *(const f16x8*)&vt[w][ni*16 + ml][q*8];
    f32x4 oa[2][4];
    #pragma unroll
    for (int mi = 0; mi < 2; mi++)
        #pragma unroll
        for (int ni = 0; ni < 4; ni++) {
            oa[mi][ni] = (f32x4){0.f,0.f,0.f,0.f};
            oa[mi][ni] = __builtin_amdgcn_mfma_f32_16x16x32_f16(ap[mi], bv[ni], oa[mi][ni], 0, 0, 0);
        }

    _Float16* co = ctxo + (size_t)(b*4 + w) * 1920;
    #pragma unroll
    for (int mi = 0; mi < 2; mi++)
        #pragma unroll
        for (int r = 0; r < 4; r++) {
            const int row = mi*16 + q*4 + r;
            if (row < 30) {
                #pragma unroll
                for (int ni = 0; ni < 4; ni++)
                    co[row*64 + ni*16 + ml] = (_Float16)oa[mi][ni][r];
            }
        }
}

// ---------- G3: outer fc1 -----------------------------------------------------
__global__ __launch_bounds__(256) void k_outer_fc1_mfma(
    const _Float16* __restrict__ ctxo,
    const _Float16* __restrict__ ow1t,
    const float* __restrict__ ob1,
    _Float16* __restrict__ hout)
{
    const int t = threadIdx.x, lane = t & 63, w = t >> 6;
    const int q = lane >> 4, ml = lane & 15;
    const int M0 = (blockIdx.x >> 3) * 128 + (w >> 1) * 64;
    const int N0 = (blockIdx.x & 7) * 128 + (w & 1) * 64;
    f32x4 acc[4][4];
    #pragma unroll
    for (int mi = 0; mi < 4; mi++)
        #pragma unroll
        for (int ni = 0; ni < 4; ni++) acc[mi][ni] = (f32x4){0.f,0.f,0.f,0.f};
    for (int ks = 0; ks < 60; ks++) {
        const int k = ks * 32 + q * 8;
        f16x8 a[4], b[4];
        #pragma unroll
        for (int mi = 0; mi < 4; mi++)
            a[mi] = *(const f16x8*)&ctxo[(size_t)(M0 + mi*16 + ml) * 1920 + k];
        #pragma unroll
        for (int ni = 0; ni < 4; ni++)
            b[ni] = *(const f16x8*)&ow1t[(size_t)(N0 + ni*16 + ml) * 1920 + k];
        #pragma unroll
        for (int mi = 0; mi < 4; mi++)
            #pragma unroll
            for (int ni = 0; ni < 4; ni++)
                acc[mi][ni] = __builtin_amdgcn_mfma_f32_16x16x32_f16(a[mi], b[ni], acc[mi][ni], 0, 0, 0);
    }
    #pragma unroll
    for (int mi = 0; mi < 4; mi++)
        #pragma unroll
        for (int ni = 0; ni < 4; ni++) {
            const int col = N0 + ni*16 + ml;
            const float bias = ob1[col];
            #pragma unroll
            for (int r = 0; r < 4; r++) {
                const int row = M0 + mi*16 + q*4 + r;
                hout[(size_t)row * 1024 + col] = (_Float16)tanh_fast(acc[mi][ni][r] + bias);
            }
        }
}

// ---------- G4: outer fc2 -----------------------------------------------------
__global__ __launch_bounds__(256) void k_outer_fc2_mfma(
    const _Float16* __restrict__ hout,
    const _Float16* __restrict__ ow2t,
    const float* __restrict__ ob2,
    float* __restrict__ out)
{
    __shared__ float red[4][64][64];
    const int t = threadIdx.x, lane = t & 63, w = t >> 6;
    const int q = lane >> 4, ml = lane & 15;
    const int M0 = (blockIdx.x / 17) * 64;
    const int N0 = (blockIdx.x % 17) * 64;
    f32x4 acc[4][4];
    #pragma unroll
    for (int mi = 0; mi < 4; mi++)
        #pragma unroll
        for (int ni = 0; ni < 4; ni++) acc[mi][ni] = (f32x4){0.f,0.f,0.f,0.f};
    for (int ks = 0; ks < 32; ks++) {
        const int k = w * 1024 + ks * 32 + q * 8;
        f16x8 a[4], b[4];
        #pragma unroll
        for (int mi = 0; mi < 4; mi++)
            a[mi] = *(const f16x8*)&hout[(size_t)(M0 + mi*16 + ml) * 4096 + k];
        #pragma unroll
        for (int ni = 0; ni < 4; ni++)
            b[ni] = *(const f16x8*)&ow2t[(size_t)(N0 + ni*16 + ml) * 4096 + k];
        #pragma unroll
        for (int mi = 0; mi < 4; mi++)
            #pragma unroll
            for (int ni = 0; ni < 4; ni++)
                acc[mi][ni] = __builtin_amdgcn_mfma_f32_16x16x32_f16(a[mi], b[ni], acc[mi][ni], 0, 0, 0);
    }
    #pragma unroll
    for (int mi = 0; mi < 4; mi++)
        #pragma unroll
        for (int ni = 0; ni < 4; ni++)
            #pragma unroll
            for (int r = 0; r < 4; r++)
                red[w][mi*16 + q*4 + r][ni*16 + ml] = acc[mi][ni][r];
    __syncthreads();
    for (int i = t; i < 4096; i += 256) {
        const int row = i >> 6, col = i & 63;
        const int n = N0 + col;
        if (n < 1080) {
            float s = red[0][row][col] + red[1][row][col] + red[2][row][col] + red[3][row][col] + ob2[n];
            out[(size_t)(M0 + row) * 1080 + n] = s;
        }
    }
}

extern "C" void kernel_launch(void* const* d_in, const int* in_sizes, int n_in,
                              void* d_out, int out_size, void* d_ws, size_t ws_size,
                              hipStream_t stream) {
    const float* x   = (const float*)d_in[0];
    const float* iwq = (const float*)d_in[1];
    const float* ibq = (const float*)d_in[2];
    const float* iwk = (const float*)d_in[3];
    const float* ibk = (const float*)d_in[4];
    const float* iwv = (const float*)d_in[5];
    const float* ibv = (const float*)d_in[6];
    const float* iw1 = (const float*)d_in[7];
    const float* ib1 = (const float*)d_in[8];
    const float* iw2 = (const float*)d_in[9];
    const float* ib2 = (const float*)d_in[10];
    const float* owq = (const float*)d_in[11];
    const float* obq = (const float*)d_in[12];
    const float* owk = (const float*)d_in[13];
    const float* obk = (const float*)d_in[14];
    const float* owv = (const float*)d_in[15];
    const float* obv = (const float*)d_in[16];
    const float* ow1 = (const float*)d_in[17];
    const float* ob1 = (const float*)d_in[18];
    const float* ow2 = (const float*)d_in[19];
    const float* ob2 = (const float*)d_in[20];

    char* ws = (char*)d_ws;
    _Float16* iw1t   = (_Float16*)(ws + 0);          // [256][160]
    _Float16* wqf    = (_Float16*)(ws + 98304);      // [64][8]
    _Float16* wkf    = (_Float16*)(ws + 99328);
    _Float16* wvf    = (_Float16*)(ws + 100352);
    _Float16* iw2t   = (_Float16*)(ws + 163840);     // [64][1024]
    _Float16* ow1t   = (_Float16*)(ws + 294912);     // [1024][1920]
    _Float16* ow2t   = (_Float16*)(ws + 4227072);    // [1088][4096]
    _Float16* flat   = (_Float16*)(ws + 13139968);   // [122880][160]
    float*    seq    = (float*)   (ws + 52461568);   // [30720][64]
    _Float16* owqt   = (_Float16*)(ws + 60325888);   // [4][64][64]
    _Float16* owkt   = (_Float16*)(ws + 60358656);
    _Float16* owvt   = (_Float16*)(ws + 60391424);
    _Float16* ctxo   = (_Float16*)(ws + 13139968);   // reuse
    _Float16* houtb  = (_Float16*)(ws + 28868608);   // reuse
    float*    out    = (float*)d_out;

    k_prep_frags<<<dim3(1), dim3(256), 0, stream>>>(iwq, ibq, iwk, ibk, iwv, ibv, wqf, wkf, wvf);
    k_tcast_iw1 <<<dim3(256), dim3(160), 0, stream>>>(iw1, iw1t);
    k_tcastT<<<dim3(16, 1),  dim3(256), 0, stream>>>(iw2, iw2t, 1024, 64, 1024);
    k_tcastT<<<dim3(30, 16), dim3(256), 0, stream>>>(ow1, ow1t, 1920, 1024, 1920);
    k_tcastT<<<dim3(64, 17), dim3(256), 0, stream>>>(ow2, ow2t, 4096, 1080, 4096);
    k_tcast_h<<<dim3(16, 4), dim3(256), 0, stream>>>(owq, owqt);
    k_tcast_h<<<dim3(16, 4), dim3(256), 0, stream>>>(owk, owkt);
    k_tcast_h<<<dim3(16, 4), dim3(256), 0, stream>>>(owv, owvt);

    k_inner_attn_mfma<<<dim3(7680), dim3(256), 0, stream>>>(x, wqf, wkf, wvf, flat);
    k_inner_ml_mfma  <<<dim3(960),  dim3(256), 0, stream>>>(flat, iw1t, iw2t, ib1, ib2, seq);
    k_outer_attn_mfma<<<dim3(1024), dim3(256), 0, stream>>>(seq, owqt, owkt, owvt, obq, obk, obv, ctxo);
    k_outer_fc1_mfma <<<dim3(256),  dim3(256), 0, stream>>>(ctxo, ow1t, ob1, houtb);
    k_outer_fc2_mfma <<<dim3(272),  dim3(256), 0, stream>>>(houtb, ow2t, ob2, out);
}

// Round 7
// 374.683 us; speedup vs baseline: 6.1926x; 1.0204x over previous
//
#include <hip/hip_runtime.h>

// DoubleAttention: B=1024, S_OUT=30, S_IN=17, D_IN=3, H=4
// Round 7: outer fc1/fc2 restructured for occupancy (latency-bound fix):
//   fc1: 1024 blocks x 2 waves, k-split-2, LDS reduce (was 256 blocks, 4 w/CU)
//   fc2: 544 blocks x 4 waves, M-tile 32, k-split-4 (was 272 blocks)
//
// 32x32x16 frag layouts (m74/m101) and 16x16x32 layouts (m89/m91) as before.
// flat k-ordering: k' = dv*20 + p  (p 0..16 valid, 17..19 zero-weighted pad)

typedef _Float16 f16x8 __attribute__((ext_vector_type(8)));
typedef _Float16 f16x4 __attribute__((ext_vector_type(4)));
typedef float    f32x4 __attribute__((ext_vector_type(4)));
typedef float    f32x16 __attribute__((ext_vector_type(16)));

union F16x8u { f16x8 v; f16x4 q[2]; };

__device__ inline float tanh_fast(float x) {
    float ax = fabsf(x);
    float e  = __expf(2.0f * ax);
    float r  = 1.0f - 2.0f / (e + 1.0f);
    return copysignf(r, x);
}

__device__ inline f32x16 zero16() {
    f32x16 z;
    #pragma unroll
    for (int i = 0; i < 16; i++) z[i] = 0.f;
    return z;
}

// ---------- prep: inner QKV weight frag arrays [64][8] (bias in k=3) --------
__global__ __launch_bounds__(256) void k_prep_frags(
    const float* __restrict__ iwq, const float* __restrict__ ibq,
    const float* __restrict__ iwk, const float* __restrict__ ibk,
    const float* __restrict__ iwv, const float* __restrict__ ibv,
    _Float16* __restrict__ wqf, _Float16* __restrict__ wkf, _Float16* __restrict__ wvf)
{
    const float SC = 0.40824829046386307f;   // 1/sqrt(6) folded into Q
    for (int i = threadIdx.x; i < 512; i += 256) {
        const int lanev = i >> 3, jj = i & 7;
        const int n = lanev & 31, grp = lanev >> 5;
        const int h = n >> 3, dk = n & 7;
        float q = 0.f, k = 0.f, v = 0.f;
        if (!grp) {
            if (jj < 3) {
                if (dk < 6) { q = iwq[h*18 + jj*6 + dk] * SC; k = iwk[h*18 + jj*6 + dk]; }
                v = iwv[h*24 + jj*8 + dk];
            } else if (jj == 3) {
                if (dk < 6) { q = ibq[h*6 + dk] * SC; k = ibk[h*6 + dk]; }
                v = ibv[h*8 + dk];
            }
        }
        wqf[i] = (_Float16)q; wkf[i] = (_Float16)k; wvf[i] = (_Float16)v;
    }
}

// ---------- tiled transpose+cast: W[K][N] f32 -> Wt[N][Kpad] f16 ------------
__global__ __launch_bounds__(256) void k_tcastT(
    const float* __restrict__ W, _Float16* __restrict__ Wt,
    int K, int N, int Kpad)
{
    __shared__ _Float16 tile[64][65];
    const int k0 = blockIdx.x * 64, n0 = blockIdx.y * 64;
    for (int i = threadIdx.x; i < 4096; i += 256) {
        const int r = i >> 6, c = i & 63;
        const int k = k0 + r, n = n0 + c;
        float v = (k < K && n < N) ? W[(size_t)k * N + n] : 0.f;
        tile[c][r] = (_Float16)v;
    }
    __syncthreads();
    for (int i = threadIdx.x; i < 4096; i += 256) {
        const int r = i >> 6, c = i & 63;
        Wt[(size_t)(n0 + r) * Kpad + k0 + c] = tile[r][c];
    }
}

// ---------- iw1t builder with k' = dv*20+p ordering, zero pads --------------
__global__ void k_tcast_iw1(const float* __restrict__ iw1, _Float16* __restrict__ iw1t)
{
    const int n = blockIdx.x;          // 0..255
    const int t = threadIdx.x;         // 0..159 = k'
    const int dv = t / 20, p = t % 20;
    float v = (p < 17) ? iw1[(p*8 + dv) * 256 + n] : 0.f;
    iw1t[n * 160 + t] = (_Float16)v;
}

// batched [H][64][64] -> per-head transposed f16
__global__ __launch_bounds__(256) void k_tcast_h(
    const float* __restrict__ W, _Float16* __restrict__ Wt)
{
    const int h = blockIdx.y;
    const int idx = blockIdx.x * 256 + threadIdx.x;
    const int n = idx >> 6, k = idx & 63;
    Wt[h * 4096 + n * 64 + k] = (_Float16)W[h * 4096 + k * 64 + n];
}

// ---------- K1: inner attention, MFMA, 1 wave per (b,s) ---------------------
__global__ __launch_bounds__(256, 3) void k_inner_attn_mfma(
    const float* __restrict__ x,
    const _Float16* __restrict__ wqf, const _Float16* __restrict__ wkf,
    const _Float16* __restrict__ wvf,
    _Float16* __restrict__ flat)
{
    __shared__ __align__(16) _Float16 lds[4][5248];
    const int t = threadIdx.x, lane = t & 63, w = t >> 6;
    const int l31 = lane & 31, grp = lane >> 5;
    const int bs = blockIdx.x * 4 + w;
    _Float16* kq  = &lds[w][0];
    _Float16* qq  = &lds[w][1152];
    _Float16* vt  = &lds[w][2304];
    _Float16* pf  = &lds[w][3456];
    _Float16* fo2 = &lds[w][4608];

    f16x8 xf;
    #pragma unroll
    for (int i = 0; i < 8; i++) xf[i] = (_Float16)0.f;
    if (grp == 0 && l31 < 17) {
        const float* xr = x + (size_t)bs * 51 + l31 * 3;
        xf[0] = (_Float16)xr[0];
        xf[1] = (_Float16)xr[1];
        xf[2] = (_Float16)xr[2];
        xf[3] = (_Float16)1.0f;
    }
    const f16x8 wq8 = *(const f16x8*)&wqf[lane * 8];
    const f16x8 wk8 = *(const f16x8*)&wkf[lane * 8];
    const f16x8 wv8 = *(const f16x8*)&wvf[lane * 8];

    f32x16 kt = __builtin_amdgcn_mfma_f32_32x32x16_f16(wk8, xf, zero16(), 0, 0, 0);
    f32x16 qt = __builtin_amdgcn_mfma_f32_32x32x16_f16(wq8, xf, zero16(), 0, 0, 0);
    f32x16 vv = __builtin_amdgcn_mfma_f32_32x32x16_f16(xf, wv8, zero16(), 0, 0, 0);

    #pragma unroll
    for (int qd = 0; qd < 4; qd++) {
        const int base = 8 * qd + 4 * grp;
        f16x4 a, b, c;
        #pragma unroll
        for (int i = 0; i < 4; i++) {
            a[i] = (_Float16)kt[4*qd + i];
            b[i] = (_Float16)qt[4*qd + i];
            c[i] = (_Float16)vv[4*qd + i];
        }
        *(f16x4*)&kq[l31 * 36 + base] = a;   // kq[j][n]
        *(f16x4*)&qq[l31 * 36 + base] = b;   // qq[p][n]
        *(f16x4*)&vt[l31 * 36 + base] = c;   // vt[n][j]
    }

    #pragma unroll
    for (int h = 0; h < 4; h++) {
        F16x8u ka, qb;
        #pragma unroll
        for (int i = 0; i < 8; i++) { ka.v[i] = (_Float16)0.f; qb.v[i] = (_Float16)0.f; }
        if (grp == 0) {
            ka.q[0] = *(const f16x4*)&kq[l31 * 36 + h * 8];
            ka.q[1] = *(const f16x4*)&kq[l31 * 36 + h * 8 + 4];
            qb.q[0] = *(const f16x4*)&qq[l31 * 36 + h * 8];
            qb.q[1] = *(const f16x4*)&qq[l31 * 36 + h * 8 + 4];
        }
        f32x16 s = __builtin_amdgcn_mfma_f32_32x32x16_f16(ka.v, qb.v, zero16(), 0, 0, 0);

        float mx = -1e30f;
        #pragma unroll
        for (int r = 0; r < 16; r++) {
            const bool val = (r < 8) || (r == 8 && grp == 0);
            if (val) mx = fmaxf(mx, s[r]);
        }
        mx = fmaxf(mx, __shfl_xor(mx, 32));
        float e[16], sum = 0.f;
        #pragma unroll
        for (int r = 0; r < 16; r++) {
            const bool val = (r < 8) || (r == 8 && grp == 0);
            e[r] = val ? __expf(s[r] - mx) : 0.f;
            sum += e[r];
        }
        sum += __shfl_xor(sum, 32);
        const float inv = __builtin_amdgcn_rcpf(sum);
        #pragma unroll
        for (int qd = 0; qd < 4; qd++) {
            f16x4 pk;
            #pragma unroll
            for (int i = 0; i < 4; i++) pk[i] = (_Float16)(e[4*qd + i] * inv);
            *(f16x4*)&pf[l31 * 36 + 8 * qd + 4 * grp] = pk;   // pf[p][j]
        }

        F16x8u pa1, pa2, vb1, vb2;
        pa1.q[0] = *(const f16x4*)&pf[l31 * 36 + grp * 8];
        pa1.q[1] = *(const f16x4*)&pf[l31 * 36 + grp * 8 + 4];
        pa2.q[0] = *(const f16x4*)&pf[l31 * 36 + 16 + grp * 8];
        pa2.q[1] = *(const f16x4*)&pf[l31 * 36 + 16 + grp * 8 + 4];
        const int vr = (h * 8 + (l31 & 7)) * 36;
        vb1.q[0] = *(const f16x4*)&vt[vr + grp * 8];
        vb1.q[1] = *(const f16x4*)&vt[vr + grp * 8 + 4];
        vb2.q[0] = *(const f16x4*)&vt[vr + 16 + grp * 8];
        vb2.q[1] = *(const f16x4*)&vt[vr + 16 + grp * 8 + 4];
        f32x16 c = __builtin_amdgcn_mfma_f32_32x32x16_f16(pa1.v, vb1.v, zero16(), 0, 0, 0);
        c = __builtin_amdgcn_mfma_f32_32x32x16_f16(pa2.v, vb2.v, c, 0, 0, 0);

        if (l31 < 8) {
            #pragma unroll
            for (int qd = 0; qd < 4; qd++) {
                const int jb = 8 * qd + 4 * grp;
                if (jb < 20) {
                    f16x4 ck;
                    #pragma unroll
                    for (int i = 0; i < 4; i++) ck[i] = (_Float16)c[4*qd + i];
                    *(f16x4*)&fo2[h * 160 + l31 * 20 + jb] = ck;
                }
            }
        }
    }

    _Float16* fg = flat + (size_t)bs * 640;
    *(f16x8*)&fg[lane * 8] = *(const f16x8*)&fo2[lane * 8];
    if (lane < 16)
        *(f16x8*)&fg[512 + lane * 8] = *(const f16x8*)&fo2[512 + lane * 8];
}

// ---------- G12: inner ML fused (fc1+tanh -> LDS -> fc2), MFMA --------------
__global__ __launch_bounds__(256) void k_inner_ml_mfma(
    const _Float16* __restrict__ flat,   // [122880][160] (k'=dv*20+p)
    const _Float16* __restrict__ iw1t,   // [256][160]    (same k' order)
    const _Float16* __restrict__ iw2t,   // [64][1024]
    const float* __restrict__ ib1, const float* __restrict__ ib2,
    float* __restrict__ seq)             // [30720][64]
{
    __shared__ __align__(16) _Float16 h1l[32][1032];
    float* red = (float*)&h1l[0][0];
    const int t = threadIdx.x, lane = t & 63, w = t >> 6;
    const int q = lane >> 4, ml = lane & 15;
    const int m0  = blockIdx.x * 128;
    const int bs0 = blockIdx.x * 32;

    for (int p = 0; p < 2; p++) {
        f32x4 acc[4][4];
        #pragma unroll
        for (int mi = 0; mi < 4; mi++)
            #pragma unroll
            for (int ni = 0; ni < 4; ni++) acc[mi][ni] = (f32x4){0.f,0.f,0.f,0.f};
        for (int ks = 0; ks < 5; ks++) {
            const int k = ks * 32 + q * 8;
            f16x8 a[4], b[4];
            #pragma unroll
            for (int mi = 0; mi < 4; mi++)
                a[mi] = *(const f16x8*)&flat[(size_t)(m0 + p*64 + mi*16 + ml) * 160 + k];
            #pragma unroll
            for (int ni = 0; ni < 4; ni++)
                b[ni] = *(const f16x8*)&iw1t[(size_t)(w*64 + ni*16 + ml) * 160 + k];
            #pragma unroll
            for (int mi = 0; mi < 4; mi++)
                #pragma unroll
                for (int ni = 0; ni < 4; ni++)
                    acc[mi][ni] = __builtin_amdgcn_mfma_f32_16x16x32_f16(a[mi], b[ni], acc[mi][ni], 0, 0, 0);
        }
        #pragma unroll
        for (int mi = 0; mi < 4; mi++)
            #pragma unroll
            for (int ni = 0; ni < 4; ni++)
                #pragma unroll
                for (int r = 0; r < 4; r++) {
                    const int row = p*64 + mi*16 + q*4 + r;
                    const int col = w*64 + ni*16 + ml;
                    const int bs_l = row >> 2, h = row & 3;
                    h1l[bs_l][h*256 + col] = (_Float16)tanh_fast(acc[mi][ni][r] + ib1[col]);
                }
    }
    __syncthreads();

    f32x4 a2[2][4];
    #pragma unroll
    for (int mi = 0; mi < 2; mi++)
        #pragma unroll
        for (int ni = 0; ni < 4; ni++) a2[mi][ni] = (f32x4){0.f,0.f,0.f,0.f};
    for (int ks = 0; ks < 8; ks++) {
        const int k = w * 256 + ks * 32 + q * 8;
        f16x8 a[2], b[4];
        #pragma unroll
        for (int mi = 0; mi < 2; mi++)
            a[mi] = *(const f16x8*)&h1l[mi*16 + ml][k];
        #pragma unroll
        for (int ni = 0; ni < 4; ni++)
            b[ni] = *(const f16x8*)&iw2t[(size_t)(ni*16 + ml) * 1024 + k];
        #pragma unroll
        for (int mi = 0; mi < 2; mi++)
            #pragma unroll
            for (int ni = 0; ni < 4; ni++)
                a2[mi][ni] = __builtin_amdgcn_mfma_f32_16x16x32_f16(a[mi], b[ni], a2[mi][ni], 0, 0, 0);
    }
    __syncthreads();
    #pragma unroll
    for (int mi = 0; mi < 2; mi++)
        #pragma unroll
        for (int ni = 0; ni < 4; ni++)
            #pragma unroll
            for (int r = 0; r < 4; r++) {
                const int row = mi*16 + q*4 + r;
                const int col = ni*16 + ml;
                red[(size_t)w*2048 + row*64 + col] = a2[mi][ni][r];
            }
    __syncthreads();
    for (int i = t; i < 2048; i += 256) {
        const int row = i >> 6, col = i & 63;
        float s = red[i] + red[2048 + i] + red[4096 + i] + red[6144 + i] + ib2[col];
        seq[(size_t)(bs0 + row) * 64 + col] = s;
    }
}

// ---------- K3: outer attention, MFMA, 1 block/b, 1 wave/head ---------------
__device__ inline void oa_proj_rows(
    const _Float16 (*seqf)[72], const _Float16* __restrict__ wt,
    const float* __restrict__ bias, _Float16 (*dst)[72], int q, int ml)
{
    f32x4 acc[2][4];
    #pragma unroll
    for (int mi = 0; mi < 2; mi++)
        #pragma unroll
        for (int ni = 0; ni < 4; ni++) acc[mi][ni] = (f32x4){0.f,0.f,0.f,0.f};
    #pragma unroll
    for (int k0 = 0; k0 < 64; k0 += 32) {
        f16x8 a[2], bb[4];
        #pragma unroll
        for (int mi = 0; mi < 2; mi++) a[mi] = *(const f16x8*)&seqf[mi*16 + ml][k0 + q*8];
        #pragma unroll
        for (int ni = 0; ni < 4; ni++) bb[ni] = *(const f16x8*)&wt[(size_t)(ni*16 + ml)*64 + k0 + q*8];
        #pragma unroll
        for (int mi = 0; mi < 2; mi++)
            #pragma unroll
            for (int ni = 0; ni < 4; ni++)
                acc[mi][ni] = __builtin_amdgcn_mfma_f32_16x16x32_f16(a[mi], bb[ni], acc[mi][ni], 0, 0, 0);
    }
    #pragma unroll
    for (int ni = 0; ni < 4; ni++) {
        const float bi = bias[ni*16 + ml];
        #pragma unroll
        for (int mi = 0; mi < 2; mi++)
            #pragma unroll
            for (int r = 0; r < 4; r++)
                dst[mi*16 + q*4 + r][ni*16 + ml] = (_Float16)(acc[mi][ni][r] + bi);
    }
}

__device__ inline void oa_proj_t(
    const _Float16 (*seqf)[72], const _Float16* __restrict__ wt,
    const float* __restrict__ bias, _Float16 (*dstT)[40], int q, int ml)
{
    f32x4 acc[2][4];
    #pragma unroll
    for (int mi = 0; mi < 2; mi++)
        #pragma unroll
        for (int ni = 0; ni < 4; ni++) acc[mi][ni] = (f32x4){0.f,0.f,0.f,0.f};
    #pragma unroll
    for (int k0 = 0; k0 < 64; k0 += 32) {
        f16x8 a[2], bb[4];
        #pragma unroll
        for (int mi = 0; mi < 2; mi++) a[mi] = *(const f16x8*)&seqf[mi*16 + ml][k0 + q*8];
        #pragma unroll
        for (int ni = 0; ni < 4; ni++) bb[ni] = *(const f16x8*)&wt[(size_t)(ni*16 + ml)*64 + k0 + q*8];
        #pragma unroll
        for (int mi = 0; mi < 2; mi++)
            #pragma unroll
            for (int ni = 0; ni < 4; ni++)
                acc[mi][ni] = __builtin_amdgcn_mfma_f32_16x16x32_f16(a[mi], bb[ni], acc[mi][ni], 0, 0, 0);
    }
    #pragma unroll
    for (int ni = 0; ni < 4; ni++) {
        const float bi = bias[ni*16 + ml];
        #pragma unroll
        for (int mi = 0; mi < 2; mi++)
            #pragma unroll
            for (int r = 0; r < 4; r++)
                dstT[ni*16 + ml][mi*16 + q*4 + r] = (_Float16)(acc[mi][ni][r] + bi);
    }
}

__global__ __launch_bounds__(256) void k_outer_attn_mfma(
    const float* __restrict__ seq,
    const _Float16* __restrict__ owqt,
    const _Float16* __restrict__ owkt,
    const _Float16* __restrict__ owvt,
    const float* __restrict__ obq, const float* __restrict__ obk,
    const float* __restrict__ obv,
    _Float16* __restrict__ ctxo)
{
    __shared__ __align__(16) _Float16 seqf[32][72];
    __shared__ __align__(16) _Float16 qf[4][32][72];
    __shared__ __align__(16) _Float16 kf[4][32][72];
    __shared__ __align__(16) _Float16 vt[4][64][40];
    __shared__ __align__(16) _Float16 pf[4][32][40];
    const int t = threadIdx.x, lane = t & 63, w = t >> 6;
    const int q = lane >> 4, ml = lane & 15;
    const int b = blockIdx.x;

    const float* sb = seq + (size_t)b * 1920;
    for (int i = t; i < 2048; i += 256) {
        const int row = i >> 6, col = i & 63;
        seqf[row][col] = (_Float16)(row < 30 ? sb[row*64 + col] : 0.0f);
    }
    __syncthreads();

    oa_proj_rows(seqf, owqt + w*4096, obq + w*64, qf[w], q, ml);
    oa_proj_rows(seqf, owkt + w*4096, obk + w*64, kf[w], q, ml);
    oa_proj_t   (seqf, owvt + w*4096, obv + w*64, vt[w], q, ml);
    __syncthreads();

    f32x4 sc[2][2];
    #pragma unroll
    for (int mi = 0; mi < 2; mi++)
        #pragma unroll
        for (int ni = 0; ni < 2; ni++) sc[mi][ni] = (f32x4){0.f,0.f,0.f,0.f};
    #pragma unroll
    for (int k0 = 0; k0 < 64; k0 += 32) {
        f16x8 aq[2], bk[2];
        #pragma unroll
        for (int mi = 0; mi < 2; mi++) aq[mi] = *(const f16x8*)&qf[w][mi*16 + ml][k0 + q*8];
        #pragma unroll
        for (int ni = 0; ni < 2; ni++) bk[ni] = *(const f16x8*)&kf[w][ni*16 + ml][k0 + q*8];
        #pragma unroll
        for (int mi = 0; mi < 2; mi++)
            #pragma unroll
            for (int ni = 0; ni < 2; ni++)
                sc[mi][ni] = __builtin_amdgcn_mfma_f32_16x16x32_f16(aq[mi], bk[ni], sc[mi][ni], 0, 0, 0);
    }

    const bool maskhi = (ml >= 14);
    #pragma unroll
    for (int mi = 0; mi < 2; mi++) {
        #pragma unroll
        for (int r = 0; r < 4; r++) {
            const float s0 = sc[mi][0][r] * 0.125f;
            const float s1 = maskhi ? -1e30f : sc[mi][1][r] * 0.125f;
            float mx = fmaxf(s0, s1);
            #pragma unroll
            for (int off = 1; off < 16; off <<= 1) mx = fmaxf(mx, __shfl_xor(mx, off, 64));
            const float e0 = __expf(s0 - mx);
            const float e1 = __expf(s1 - mx);
            float sm = e0 + e1;
            #pragma unroll
            for (int off = 1; off < 16; off <<= 1) sm += __shfl_xor(sm, off, 64);
            const float inv = 1.0f / sm;
            pf[w][mi*16 + q*4 + r][ml]      = (_Float16)(e0 * inv);
            pf[w][mi*16 + q*4 + r][16 + ml] = (_Float16)(e1 * inv);
        }
    }
    __syncthreads();

    f16x8 ap[2], bv[4];
    #pragma unroll
    for (int mi = 0; mi < 2; mi++) ap[mi] = *(const f16x8*)&pf[w][mi*16 + ml][q*8];
    #pragma unroll
    for (int ni = 0; ni < 4; ni++) bv[ni] = *(const f16x8*)&vt[w][ni*16 + ml][q*8];
    f32x4 oa[2][4];
    #pragma unroll
    for (int mi = 0; mi < 2; mi++)
        #pragma unroll
        for (int ni = 0; ni < 4; ni++) {
            oa[mi][ni] = (f32x4){0.f,0.f,0.f,0.f};
            oa[mi][ni] = __builtin_amdgcn_mfma_f32_16x16x32_f16(ap[mi], bv[ni], oa[mi][ni], 0, 0, 0);
        }

    _Float16* co = ctxo + (size_t)(b*4 + w) * 1920;
    #pragma unroll
    for (int mi = 0; mi < 2; mi++)
        #pragma unroll
        for (int r = 0; r < 4; r++) {
            const int row = mi*16 + q*4 + r;
            if (row < 30) {
                #pragma unroll
                for (int ni = 0; ni < 4; ni++)
                    co[row*64 + ni*16 + ml] = (_Float16)oa[mi][ni][r];
            }
        }
}

// ---------- G3: outer fc1  [4096][1024] = ctxo x ow1t, tanh -> f16 ----------
// 1024 blocks x 128 thr (2 waves); tile 64x64; k-split-2 (960 each); LDS reduce
__global__ __launch_bounds__(128) void k_outer_fc1_mfma(
    const _Float16* __restrict__ ctxo,   // [4096][1920]
    const _Float16* __restrict__ ow1t,   // [1024][1920]
    const float* __restrict__ ob1,
    _Float16* __restrict__ hout)         // [4096][1024]
{
    __shared__ float red[2][64][65];     // +1 pad: conflict-free
    const int t = threadIdx.x, lane = t & 63, w = t >> 6;
    const int q = lane >> 4, ml = lane & 15;
    const int M0 = (blockIdx.x >> 4) * 64;   // 64 M-tiles
    const int N0 = (blockIdx.x & 15) * 64;   // 16 N-tiles
    f32x4 acc[4][4];
    #pragma unroll
    for (int mi = 0; mi < 4; mi++)
        #pragma unroll
        for (int ni = 0; ni < 4; ni++) acc[mi][ni] = (f32x4){0.f,0.f,0.f,0.f};
    for (int ks = 0; ks < 30; ks++) {
        const int k = w * 960 + ks * 32 + q * 8;
        f16x8 a[4], b[4];
        #pragma unroll
        for (int mi = 0; mi < 4; mi++)
            a[mi] = *(const f16x8*)&ctxo[(size_t)(M0 + mi*16 + ml) * 1920 + k];
        #pragma unroll
        for (int ni = 0; ni < 4; ni++)
            b[ni] = *(const f16x8*)&ow1t[(size_t)(N0 + ni*16 + ml) * 1920 + k];
        #pragma unroll
        for (int mi = 0; mi < 4; mi++)
            #pragma unroll
            for (int ni = 0; ni < 4; ni++)
                acc[mi][ni] = __builtin_amdgcn_mfma_f32_16x16x32_f16(a[mi], b[ni], acc[mi][ni], 0, 0, 0);
    }
    #pragma unroll
    for (int mi = 0; mi < 4; mi++)
        #pragma unroll
        for (int ni = 0; ni < 4; ni++)
            #pragma unroll
            for (int r = 0; r < 4; r++)
                red[w][mi*16 + q*4 + r][ni*16 + ml] = acc[mi][ni][r];
    __syncthreads();
    for (int i = t; i < 4096; i += 128) {
        const int row = i >> 6, col = i & 63;
        const float s = red[0][row][col] + red[1][row][col] + ob1[N0 + col];
        hout[(size_t)(M0 + row) * 1024 + N0 + col] = (_Float16)tanh_fast(s);
    }
}

// ---------- G4: outer fc2  [1024][1080] = hout x ow2t + ob2 -----------------
// 544 blocks x 256 thr (4 waves); tile 32x64; k-split-4 (1024 each); LDS reduce
__global__ __launch_bounds__(256) void k_outer_fc2_mfma(
    const _Float16* __restrict__ hout,   // [1024][4096]
    const _Float16* __restrict__ ow2t,   // [1088][4096]
    const float* __restrict__ ob2,
    float* __restrict__ out)             // [1024][1080]
{
    __shared__ float red[4][32][65];     // +1 pad: conflict-free
    const int t = threadIdx.x, lane = t & 63, w = t >> 6;
    const int q = lane >> 4, ml = lane & 15;
    const int M0 = (blockIdx.x / 17) * 32;   // 32 M-tiles
    const int N0 = (blockIdx.x % 17) * 64;   // 17 N-tiles
    f32x4 acc[2][4];
    #pragma unroll
    for (int mi = 0; mi < 2; mi++)
        #pragma unroll
        for (int ni = 0; ni < 4; ni++) acc[mi][ni] = (f32x4){0.f,0.f,0.f,0.f};
    for (int ks = 0; ks < 32; ks++) {
        const int k = w * 1024 + ks * 32 + q * 8;
        f16x8 a[2], b[4];
        #pragma unroll
        for (int mi = 0; mi < 2; mi++)
            a[mi] = *(const f16x8*)&hout[(size_t)(M0 + mi*16 + ml) * 4096 + k];
        #pragma unroll
        for (int ni = 0; ni < 4; ni++)
            b[ni] = *(const f16x8*)&ow2t[(size_t)(N0 + ni*16 + ml) * 4096 + k];
        #pragma unroll
        for (int mi = 0; mi < 2; mi++)
            #pragma unroll
            for (int ni = 0; ni < 4; ni++)
                acc[mi][ni] = __builtin_amdgcn_mfma_f32_16x16x32_f16(a[mi], b[ni], acc[mi][ni], 0, 0, 0);
    }
    #pragma unroll
    for (int mi = 0; mi < 2; mi++)
        #pragma unroll
        for (int ni = 0; ni < 4; ni++)
            #pragma unroll
            for (int r = 0; r < 4; r++)
                red[w][mi*16 + q*4 + r][ni*16 + ml] = acc[mi][ni][r];
    __syncthreads();
    for (int i = t; i < 2048; i += 256) {
        const int row = i >> 6, col = i & 63;
        const int n = N0 + col;
        if (n < 1080) {
            float s = red[0][row][col] + red[1][row][col] + red[2][row][col] + red[3][row][col] + ob2[n];
            out[(size_t)(M0 + row) * 1080 + n] = s;
        }
    }
}

extern "C" void kernel_launch(void* const* d_in, const int* in_sizes, int n_in,
                              void* d_out, int out_size, void* d_ws, size_t ws_size,
                              hipStream_t stream) {
    const float* x   = (const float*)d_in[0];
    const float* iwq = (const float*)d_in[1];
    const float* ibq = (const float*)d_in[2];
    const float* iwk = (const float*)d_in[3];
    const float* ibk = (const float*)d_in[4];
    const float* iwv = (const float*)d_in[5];
    const float* ibv = (const float*)d_in[6];
    const float* iw1 = (const float*)d_in[7];
    const float* ib1 = (const float*)d_in[8];
    const float* iw2 = (const float*)d_in[9];
    const float* ib2 = (const float*)d_in[10];
    const float* owq = (const float*)d_in[11];
    const float* obq = (const float*)d_in[12];
    const float* owk = (const float*)d_in[13];
    const float* obk = (const float*)d_in[14];
    const float* owv = (const float*)d_in[15];
    const float* obv = (const float*)d_in[16];
    const float* ow1 = (const float*)d_in[17];
    const float* ob1 = (const float*)d_in[18];
    const float* ow2 = (const float*)d_in[19];
    const float* ob2 = (const float*)d_in[20];

    char* ws = (char*)d_ws;
    _Float16* iw1t   = (_Float16*)(ws + 0);          // [256][160]
    _Float16* wqf    = (_Float16*)(ws + 98304);      // [64][8]
    _Float16* wkf    = (_Float16*)(ws + 99328);
    _Float16* wvf    = (_Float16*)(ws + 100352);
    _Float16* iw2t   = (_Float16*)(ws + 163840);     // [64][1024]
    _Float16* ow1t   = (_Float16*)(ws + 294912);     // [1024][1920]
    _Float16* ow2t   = (_Float16*)(ws + 4227072);    // [1088][4096]
    _Float16* flat   = (_Float16*)(ws + 13139968);   // [122880][160]
    float*    seq    = (float*)   (ws + 52461568);   // [30720][64]
    _Float16* owqt   = (_Float16*)(ws + 60325888);   // [4][64][64]
    _Float16* owkt   = (_Float16*)(ws + 60358656);
    _Float16* owvt   = (_Float16*)(ws + 60391424);
    _Float16* ctxo   = (_Float16*)(ws + 13139968);   // reuse
    _Float16* houtb  = (_Float16*)(ws + 28868608);   // reuse
    float*    out    = (float*)d_out;

    k_prep_frags<<<dim3(1), dim3(256), 0, stream>>>(iwq, ibq, iwk, ibk, iwv, ibv, wqf, wkf, wvf);
    k_tcast_iw1 <<<dim3(256), dim3(160), 0, stream>>>(iw1, iw1t);
    k_tcastT<<<dim3(16, 1),  dim3(256), 0, stream>>>(iw2, iw2t, 1024, 64, 1024);
    k_tcastT<<<dim3(30, 16), dim3(256), 0, stream>>>(ow1, ow1t, 1920, 1024, 1920);
    k_tcastT<<<dim3(64, 17), dim3(256), 0, stream>>>(ow2, ow2t, 4096, 1080, 4096);
    k_tcast_h<<<dim3(16, 4), dim3(256), 0, stream>>>(owq, owqt);
    k_tcast_h<<<dim3(16, 4), dim3(256), 0, stream>>>(owk, owkt);
    k_tcast_h<<<dim3(16, 4), dim3(256), 0, stream>>>(owv, owvt);

    k_inner_attn_mfma<<<dim3(7680), dim3(256), 0, stream>>>(x, wqf, wkf, wvf, flat);
    k_inner_ml_mfma  <<<dim3(960),  dim3(256), 0, stream>>>(flat, iw1t, iw2t, ib1, ib2, seq);
    k_outer_attn_mfma<<<dim3(1024), dim3(256), 0, stream>>>(seq, owqt, owkt, owvt, obq, obk, obv, ctxo);
    k_outer_fc1_mfma <<<dim3(1024), dim3(128), 0, stream>>>(ctxo, ow1t, ob1, houtb);
    k_outer_fc2_mfma <<<dim3(544),  dim3(256), 0, stream>>>(houtb, ow2t, ob2, out);
}

// Round 8
// 335.183 us; speedup vs baseline: 6.9223x; 1.1178x over previous
//
#include <hip/hip_runtime.h>

// DoubleAttention: B=1024, S_OUT=30, S_IN=17, D_IN=3, H=4
// Round 8: fc2 block-level K-split-4 + reduce; register ping-pong prefetch in
// fc1/fc2 K-loops; all prep kernels merged into one dispatch (13 -> 7).
//
// ws map (bytes):
//   iw1t @0  wq/wk/wvf @98304..  iw2t @163840  ow1t @294912  ow2t @4227072
//   flat @13139968 (39.3MB, dead after inner_ml)
//   seq  @52461568  owqt/owkt/owvt @60325888..60424192
//   ctxo @13139968 (reuse; dead after fc1)
//   part @13139968 (reuse; [4][1024][1080] f32, 17.7MB)
//   hout @40000000 ([1024][4096] f16, 8.4MB; inside dead flat region)

typedef _Float16 f16x8 __attribute__((ext_vector_type(8)));
typedef _Float16 f16x4 __attribute__((ext_vector_type(4)));
typedef float    f32x4 __attribute__((ext_vector_type(4)));
typedef float    f32x16 __attribute__((ext_vector_type(16)));

union F16x8u { f16x8 v; f16x4 q[2]; };

__device__ inline float tanh_fast(float x) {
    float ax = fabsf(x);
    float e  = __expf(2.0f * ax);
    float r  = 1.0f - 2.0f / (e + 1.0f);
    return copysignf(r, x);
}

__device__ inline f32x16 zero16() {
    f32x16 z;
    #pragma unroll
    for (int i = 0; i < 16; i++) z[i] = 0.f;
    return z;
}

// ---------- merged prep: frags + all transposes in ONE dispatch -------------
__device__ inline void tcast_tile(
    const float* __restrict__ W, _Float16* __restrict__ Wt,
    int tileIdx, int nkx, int K, int N, int Kpad,
    _Float16 (*tile)[65], int t)
{
    const int kx = tileIdx % nkx, ny = tileIdx / nkx;
    const int k0 = kx * 64, n0 = ny * 64;
    for (int i = t; i < 4096; i += 256) {
        const int r = i >> 6, c = i & 63;
        const int k = k0 + r, n = n0 + c;
        float v = (k < K && n < N) ? W[(size_t)k * N + n] : 0.f;
        tile[c][r] = (_Float16)v;
    }
    __syncthreads();
    for (int i = t; i < 4096; i += 256) {
        const int r = i >> 6, c = i & 63;
        Wt[(size_t)(n0 + r) * Kpad + k0 + c] = tile[r][c];
    }
}

__global__ __launch_bounds__(256) void k_prep_all(
    const float* __restrict__ iwq, const float* __restrict__ ibq,
    const float* __restrict__ iwk, const float* __restrict__ ibk,
    const float* __restrict__ iwv, const float* __restrict__ ibv,
    const float* __restrict__ iw1, const float* __restrict__ iw2,
    const float* __restrict__ ow1, const float* __restrict__ ow2,
    const float* __restrict__ owq, const float* __restrict__ owk,
    const float* __restrict__ owv,
    _Float16* __restrict__ wqf, _Float16* __restrict__ wkf,
    _Float16* __restrict__ wvf,
    _Float16* __restrict__ iw1t, _Float16* __restrict__ iw2t,
    _Float16* __restrict__ ow1t, _Float16* __restrict__ ow2t,
    _Float16* __restrict__ owqt, _Float16* __restrict__ owkt,
    _Float16* __restrict__ owvt)
{
    __shared__ _Float16 tile[64][65];
    const int b = blockIdx.x, t = threadIdx.x;
    if (b == 0) {
        const float SC = 0.40824829046386307f;   // 1/sqrt(6) folded into Q
        for (int i = t; i < 512; i += 256) {
            const int lanev = i >> 3, jj = i & 7;
            const int n = lanev & 31, grp = lanev >> 5;
            const int h = n >> 3, dk = n & 7;
            float q = 0.f, k = 0.f, v = 0.f;
            if (!grp) {
                if (jj < 3) {
                    if (dk < 6) { q = iwq[h*18 + jj*6 + dk] * SC; k = iwk[h*18 + jj*6 + dk]; }
                    v = iwv[h*24 + jj*8 + dk];
                } else if (jj == 3) {
                    if (dk < 6) { q = ibq[h*6 + dk] * SC; k = ibk[h*6 + dk]; }
                    v = ibv[h*8 + dk];
                }
            }
            wqf[i] = (_Float16)q; wkf[i] = (_Float16)k; wvf[i] = (_Float16)v;
        }
    } else if (b < 161) {
        const int idx = (b - 1) * 256 + t;        // 40960 = 256n x 160k'
        if (idx < 40960) {
            const int n = idx / 160, kp = idx - n * 160;
            const int dv = kp / 20, p = kp - dv * 20;
            float v = (p < 17) ? iw1[(p*8 + dv) * 256 + n] : 0.f;
            iw1t[n * 160 + kp] = (_Float16)v;
        }
    } else if (b < 177) {
        tcast_tile(iw2, iw2t, b - 161, 16, 1024, 64, 1024, tile, t);
    } else if (b < 657) {
        tcast_tile(ow1, ow1t, b - 177, 30, 1920, 1024, 1920, tile, t);
    } else if (b < 1745) {
        tcast_tile(ow2, ow2t, b - 657, 64, 4096, 1080, 4096, tile, t);
    } else {
        const int s = b - 1745;                    // 192 = 3 mats x 4 h x 16
        const int mat = s >> 6, rem = s & 63;
        const int h = rem >> 4, blk = rem & 15;
        const int idx = blk * 256 + t;
        const int n = idx >> 6, k = idx & 63;
        const float* W = (mat == 0) ? owq : (mat == 1) ? owk : owv;
        _Float16* Wt   = (mat == 0) ? owqt : (mat == 1) ? owkt : owvt;
        Wt[h * 4096 + n * 64 + k] = (_Float16)W[h * 4096 + k * 64 + n];
    }
}

// ---------- K1: inner attention, MFMA, 1 wave per (b,s) ---------------------
__global__ __launch_bounds__(256, 3) void k_inner_attn_mfma(
    const float* __restrict__ x,
    const _Float16* __restrict__ wqf, const _Float16* __restrict__ wkf,
    const _Float16* __restrict__ wvf,
    _Float16* __restrict__ flat)
{
    __shared__ __align__(16) _Float16 lds[4][5248];
    const int t = threadIdx.x, lane = t & 63, w = t >> 6;
    const int l31 = lane & 31, grp = lane >> 5;
    const int bs = blockIdx.x * 4 + w;
    _Float16* kq  = &lds[w][0];
    _Float16* qq  = &lds[w][1152];
    _Float16* vt  = &lds[w][2304];
    _Float16* pf  = &lds[w][3456];
    _Float16* fo2 = &lds[w][4608];

    f16x8 xf;
    #pragma unroll
    for (int i = 0; i < 8; i++) xf[i] = (_Float16)0.f;
    if (grp == 0 && l31 < 17) {
        const float* xr = x + (size_t)bs * 51 + l31 * 3;
        xf[0] = (_Float16)xr[0];
        xf[1] = (_Float16)xr[1];
        xf[2] = (_Float16)xr[2];
        xf[3] = (_Float16)1.0f;
    }
    const f16x8 wq8 = *(const f16x8*)&wqf[lane * 8];
    const f16x8 wk8 = *(const f16x8*)&wkf[lane * 8];
    const f16x8 wv8 = *(const f16x8*)&wvf[lane * 8];

    f32x16 kt = __builtin_amdgcn_mfma_f32_32x32x16_f16(wk8, xf, zero16(), 0, 0, 0);
    f32x16 qt = __builtin_amdgcn_mfma_f32_32x32x16_f16(wq8, xf, zero16(), 0, 0, 0);
    f32x16 vv = __builtin_amdgcn_mfma_f32_32x32x16_f16(xf, wv8, zero16(), 0, 0, 0);

    #pragma unroll
    for (int qd = 0; qd < 4; qd++) {
        const int base = 8 * qd + 4 * grp;
        f16x4 a, b, c;
        #pragma unroll
        for (int i = 0; i < 4; i++) {
            a[i] = (_Float16)kt[4*qd + i];
            b[i] = (_Float16)qt[4*qd + i];
            c[i] = (_Float16)vv[4*qd + i];
        }
        *(f16x4*)&kq[l31 * 36 + base] = a;   // kq[j][n]
        *(f16x4*)&qq[l31 * 36 + base] = b;   // qq[p][n]
        *(f16x4*)&vt[l31 * 36 + base] = c;   // vt[n][j]
    }

    #pragma unroll
    for (int h = 0; h < 4; h++) {
        F16x8u ka, qb;
        #pragma unroll
        for (int i = 0; i < 8; i++) { ka.v[i] = (_Float16)0.f; qb.v[i] = (_Float16)0.f; }
        if (grp == 0) {
            ka.q[0] = *(const f16x4*)&kq[l31 * 36 + h * 8];
            ka.q[1] = *(const f16x4*)&kq[l31 * 36 + h * 8 + 4];
            qb.q[0] = *(const f16x4*)&qq[l31 * 36 + h * 8];
            qb.q[1] = *(const f16x4*)&qq[l31 * 36 + h * 8 + 4];
        }
        f32x16 s = __builtin_amdgcn_mfma_f32_32x32x16_f16(ka.v, qb.v, zero16(), 0, 0, 0);

        float mx = -1e30f;
        #pragma unroll
        for (int r = 0; r < 16; r++) {
            const bool val = (r < 8) || (r == 8 && grp == 0);
            if (val) mx = fmaxf(mx, s[r]);
        }
        mx = fmaxf(mx, __shfl_xor(mx, 32));
        float e[16], sum = 0.f;
        #pragma unroll
        for (int r = 0; r < 16; r++) {
            const bool val = (r < 8) || (r == 8 && grp == 0);
            e[r] = val ? __expf(s[r] - mx) : 0.f;
            sum += e[r];
        }
        sum += __shfl_xor(sum, 32);
        const float inv = __builtin_amdgcn_rcpf(sum);
        #pragma unroll
        for (int qd = 0; qd < 4; qd++) {
            f16x4 pk;
            #pragma unroll
            for (int i = 0; i < 4; i++) pk[i] = (_Float16)(e[4*qd + i] * inv);
            *(f16x4*)&pf[l31 * 36 + 8 * qd + 4 * grp] = pk;   // pf[p][j]
        }

        F16x8u pa1, pa2, vb1, vb2;
        pa1.q[0] = *(const f16x4*)&pf[l31 * 36 + grp * 8];
        pa1.q[1] = *(const f16x4*)&pf[l31 * 36 + grp * 8 + 4];
        pa2.q[0] = *(const f16x4*)&pf[l31 * 36 + 16 + grp * 8];
        pa2.q[1] = *(const f16x4*)&pf[l31 * 36 + 16 + grp * 8 + 4];
        const int vr = (h * 8 + (l31 & 7)) * 36;
        vb1.q[0] = *(const f16x4*)&vt[vr + grp * 8];
        vb1.q[1] = *(const f16x4*)&vt[vr + grp * 8 + 4];
        vb2.q[0] = *(const f16x4*)&vt[vr + 16 + grp * 8];
        vb2.q[1] = *(const f16x4*)&vt[vr + 16 + grp * 8 + 4];
        f32x16 c = __builtin_amdgcn_mfma_f32_32x32x16_f16(pa1.v, vb1.v, zero16(), 0, 0, 0);
        c = __builtin_amdgcn_mfma_f32_32x32x16_f16(pa2.v, vb2.v, c, 0, 0, 0);

        if (l31 < 8) {
            #pragma unroll
            for (int qd = 0; qd < 4; qd++) {
                const int jb = 8 * qd + 4 * grp;
                if (jb < 20) {
                    f16x4 ck;
                    #pragma unroll
                    for (int i = 0; i < 4; i++) ck[i] = (_Float16)c[4*qd + i];
                    *(f16x4*)&fo2[h * 160 + l31 * 20 + jb] = ck;
                }
            }
        }
    }

    _Float16* fg = flat + (size_t)bs * 640;
    *(f16x8*)&fg[lane * 8] = *(const f16x8*)&fo2[lane * 8];
    if (lane < 16)
        *(f16x8*)&fg[512 + lane * 8] = *(const f16x8*)&fo2[512 + lane * 8];
}

// ---------- G12: inner ML fused (fc1+tanh -> LDS -> fc2), MFMA --------------
__global__ __launch_bounds__(256) void k_inner_ml_mfma(
    const _Float16* __restrict__ flat,   // [122880][160] (k'=dv*20+p)
    const _Float16* __restrict__ iw1t,   // [256][160]
    const _Float16* __restrict__ iw2t,   // [64][1024]
    const float* __restrict__ ib1, const float* __restrict__ ib2,
    float* __restrict__ seq)             // [30720][64]
{
    __shared__ __align__(16) _Float16 h1l[32][1032];
    float* red = (float*)&h1l[0][0];
    const int t = threadIdx.x, lane = t & 63, w = t >> 6;
    const int q = lane >> 4, ml = lane & 15;
    const int m0  = blockIdx.x * 128;
    const int bs0 = blockIdx.x * 32;

    for (int p = 0; p < 2; p++) {
        f32x4 acc[4][4];
        #pragma unroll
        for (int mi = 0; mi < 4; mi++)
            #pragma unroll
            for (int ni = 0; ni < 4; ni++) acc[mi][ni] = (f32x4){0.f,0.f,0.f,0.f};
        for (int ks = 0; ks < 5; ks++) {
            const int k = ks * 32 + q * 8;
            f16x8 a[4], b[4];
            #pragma unroll
            for (int mi = 0; mi < 4; mi++)
                a[mi] = *(const f16x8*)&flat[(size_t)(m0 + p*64 + mi*16 + ml) * 160 + k];
            #pragma unroll
            for (int ni = 0; ni < 4; ni++)
                b[ni] = *(const f16x8*)&iw1t[(size_t)(w*64 + ni*16 + ml) * 160 + k];
            #pragma unroll
            for (int mi = 0; mi < 4; mi++)
                #pragma unroll
                for (int ni = 0; ni < 4; ni++)
                    acc[mi][ni] = __builtin_amdgcn_mfma_f32_16x16x32_f16(a[mi], b[ni], acc[mi][ni], 0, 0, 0);
        }
        #pragma unroll
        for (int mi = 0; mi < 4; mi++)
            #pragma unroll
            for (int ni = 0; ni < 4; ni++)
                #pragma unroll
                for (int r = 0; r < 4; r++) {
                    const int row = p*64 + mi*16 + q*4 + r;
                    const int col = w*64 + ni*16 + ml;
                    const int bs_l = row >> 2, h = row & 3;
                    h1l[bs_l][h*256 + col] = (_Float16)tanh_fast(acc[mi][ni][r] + ib1[col]);
                }
    }
    __syncthreads();

    f32x4 a2[2][4];
    #pragma unroll
    for (int mi = 0; mi < 2; mi++)
        #pragma unroll
        for (int ni = 0; ni < 4; ni++) a2[mi][ni] = (f32x4){0.f,0.f,0.f,0.f};
    for (int ks = 0; ks < 8; ks++) {
        const int k = w * 256 + ks * 32 + q * 8;
        f16x8 a[2], b[4];
        #pragma unroll
        for (int mi = 0; mi < 2; mi++)
            a[mi] = *(const f16x8*)&h1l[mi*16 + ml][k];
        #pragma unroll
        for (int ni = 0; ni < 4; ni++)
            b[ni] = *(const f16x8*)&iw2t[(size_t)(ni*16 + ml) * 1024 + k];
        #pragma unroll
        for (int mi = 0; mi < 2; mi++)
            #pragma unroll
            for (int ni = 0; ni < 4; ni++)
                a2[mi][ni] = __builtin_amdgcn_mfma_f32_16x16x32_f16(a[mi], b[ni], a2[mi][ni], 0, 0, 0);
    }
    __syncthreads();
    #pragma unroll
    for (int mi = 0; mi < 2; mi++)
        #pragma unroll
        for (int ni = 0; ni < 4; ni++)
            #pragma unroll
            for (int r = 0; r < 4; r++) {
                const int row = mi*16 + q*4 + r;
                const int col = ni*16 + ml;
                red[(size_t)w*2048 + row*64 + col] = a2[mi][ni][r];
            }
    __syncthreads();
    for (int i = t; i < 2048; i += 256) {
        const int row = i >> 6, col = i & 63;
        float s = red[i] + red[2048 + i] + red[4096 + i] + red[6144 + i] + ib2[col];
        seq[(size_t)(bs0 + row) * 64 + col] = s;
    }
}

// ---------- K3: outer attention, MFMA, 1 block/b, 1 wave/head ---------------
__device__ inline void oa_proj_rows(
    const _Float16 (*seqf)[72], const _Float16* __restrict__ wt,
    const float* __restrict__ bias, _Float16 (*dst)[72], int q, int ml)
{
    f32x4 acc[2][4];
    #pragma unroll
    for (int mi = 0; mi < 2; mi++)
        #pragma unroll
        for (int ni = 0; ni < 4; ni++) acc[mi][ni] = (f32x4){0.f,0.f,0.f,0.f};
    #pragma unroll
    for (int k0 = 0; k0 < 64; k0 += 32) {
        f16x8 a[2], bb[4];
        #pragma unroll
        for (int mi = 0; mi < 2; mi++) a[mi] = *(const f16x8*)&seqf[mi*16 + ml][k0 + q*8];
        #pragma unroll
        for (int ni = 0; ni < 4; ni++) bb[ni] = *(const f16x8*)&wt[(size_t)(ni*16 + ml)*64 + k0 + q*8];
        #pragma unroll
        for (int mi = 0; mi < 2; mi++)
            #pragma unroll
            for (int ni = 0; ni < 4; ni++)
                acc[mi][ni] = __builtin_amdgcn_mfma_f32_16x16x32_f16(a[mi], bb[ni], acc[mi][ni], 0, 0, 0);
    }
    #pragma unroll
    for (int ni = 0; ni < 4; ni++) {
        const float bi = bias[ni*16 + ml];
        #pragma unroll
        for (int mi = 0; mi < 2; mi++)
            #pragma unroll
            for (int r = 0; r < 4; r++)
                dst[mi*16 + q*4 + r][ni*16 + ml] = (_Float16)(acc[mi][ni][r] + bi);
    }
}

__device__ inline void oa_proj_t(
    const _Float16 (*seqf)[72], const _Float16* __restrict__ wt,
    const float* __restrict__ bias, _Float16 (*dstT)[40], int q, int ml)
{
    f32x4 acc[2][4];
    #pragma unroll
    for (int mi = 0; mi < 2; mi++)
        #pragma unroll
        for (int ni = 0; ni < 4; ni++) acc[mi][ni] = (f32x4){0.f,0.f,0.f,0.f};
    #pragma unroll
    for (int k0 = 0; k0 < 64; k0 += 32) {
        f16x8 a[2], bb[4];
        #pragma unroll
        for (int mi = 0; mi < 2; mi++) a[mi] = *(const f16x8*)&seqf[mi*16 + ml][k0 + q*8];
        #pragma unroll
        for (int ni = 0; ni < 4; ni++) bb[ni] = *(const f16x8*)&wt[(size_t)(ni*16 + ml)*64 + k0 + q*8];
        #pragma unroll
        for (int mi = 0; mi < 2; mi++)
            #pragma unroll
            for (int ni = 0; ni < 4; ni++)
                acc[mi][ni] = __builtin_amdgcn_mfma_f32_16x16x32_f16(a[mi], bb[ni], acc[mi][ni], 0, 0, 0);
    }
    #pragma unroll
    for (int ni = 0; ni < 4; ni++) {
        const float bi = bias[ni*16 + ml];
        #pragma unroll
        for (int mi = 0; mi < 2; mi++)
            #pragma unroll
            for (int r = 0; r < 4; r++)
                dstT[ni*16 + ml][mi*16 + q*4 + r] = (_Float16)(acc[mi][ni][r] + bi);
    }
}

__global__ __launch_bounds__(256) void k_outer_attn_mfma(
    const float* __restrict__ seq,
    const _Float16* __restrict__ owqt,
    const _Float16* __restrict__ owkt,
    const _Float16* __restrict__ owvt,
    const float* __restrict__ obq, const float* __restrict__ obk,
    const float* __restrict__ obv,
    _Float16* __restrict__ ctxo)
{
    __shared__ __align__(16) _Float16 seqf[32][72];
    __shared__ __align__(16) _Float16 qf[4][32][72];
    __shared__ __align__(16) _Float16 kf[4][32][72];
    __shared__ __align__(16) _Float16 vt[4][64][40];
    __shared__ __align__(16) _Float16 pf[4][32][40];
    const int t = threadIdx.x, lane = t & 63, w = t >> 6;
    const int q = lane >> 4, ml = lane & 15;
    const int b = blockIdx.x;

    const float* sb = seq + (size_t)b * 1920;
    for (int i = t; i < 2048; i += 256) {
        const int row = i >> 6, col = i & 63;
        seqf[row][col] = (_Float16)(row < 30 ? sb[row*64 + col] : 0.0f);
    }
    __syncthreads();

    oa_proj_rows(seqf, owqt + w*4096, obq + w*64, qf[w], q, ml);
    oa_proj_rows(seqf, owkt + w*4096, obk + w*64, kf[w], q, ml);
    oa_proj_t   (seqf, owvt + w*4096, obv + w*64, vt[w], q, ml);
    __syncthreads();

    f32x4 sc[2][2];
    #pragma unroll
    for (int mi = 0; mi < 2; mi++)
        #pragma unroll
        for (int ni = 0; ni < 2; ni++) sc[mi][ni] = (f32x4){0.f,0.f,0.f,0.f};
    #pragma unroll
    for (int k0 = 0; k0 < 64; k0 += 32) {
        f16x8 aq[2], bk[2];
        #pragma unroll
        for (int mi = 0; mi < 2; mi++) aq[mi] = *(const f16x8*)&qf[w][mi*16 + ml][k0 + q*8];
        #pragma unroll
        for (int ni = 0; ni < 2; ni++) bk[ni] = *(const f16x8*)&kf[w][ni*16 + ml][k0 + q*8];
        #pragma unroll
        for (int mi = 0; mi < 2; mi++)
            #pragma unroll
            for (int ni = 0; ni < 2; ni++)
                sc[mi][ni] = __builtin_amdgcn_mfma_f32_16x16x32_f16(aq[mi], bk[ni], sc[mi][ni], 0, 0, 0);
    }

    const bool maskhi = (ml >= 14);
    #pragma unroll
    for (int mi = 0; mi < 2; mi++) {
        #pragma unroll
        for (int r = 0; r < 4; r++) {
            const float s0 = sc[mi][0][r] * 0.125f;
            const float s1 = maskhi ? -1e30f : sc[mi][1][r] * 0.125f;
            float mx = fmaxf(s0, s1);
            #pragma unroll
            for (int off = 1; off < 16; off <<= 1) mx = fmaxf(mx, __shfl_xor(mx, off, 64));
            const float e0 = __expf(s0 - mx);
            const float e1 = __expf(s1 - mx);
            float sm = e0 + e1;
            #pragma unroll
            for (int off = 1; off < 16; off <<= 1) sm += __shfl_xor(sm, off, 64);
            const float inv = 1.0f / sm;
            pf[w][mi*16 + q*4 + r][ml]      = (_Float16)(e0 * inv);
            pf[w][mi*16 + q*4 + r][16 + ml] = (_Float16)(e1 * inv);
        }
    }
    __syncthreads();

    f16x8 ap[2], bv[4];
    #pragma unroll
    for (int mi = 0; mi < 2; mi++) ap[mi] = *(const f16x8*)&pf[w][mi*16 + ml][q*8];
    #pragma unroll
    for (int ni = 0; ni < 4; ni++) bv[ni] = *(const f16x8*)&vt[w][ni*16 + ml][q*8];
    f32x4 oa[2][4];
    #pragma unroll
    for (int mi = 0; mi < 2; mi++)
        #pragma unroll
        for (int ni = 0; ni < 4; ni++) {
            oa[mi][ni] = (f32x4){0.f,0.f,0.f,0.f};
            oa[mi][ni] = __builtin_amdgcn_mfma_f32_16x16x32_f16(ap[mi], bv[ni], oa[mi][ni], 0, 0, 0);
        }

    _Float16* co = ctxo + (size_t)(b*4 + w) * 1920;
    #pragma unroll
    for (int mi = 0; mi < 2; mi++)
        #pragma unroll
        for (int r = 0; r < 4; r++) {
            const int row = mi*16 + q*4 + r;
            if (row < 30) {
                #pragma unroll
                for (int ni = 0; ni < 4; ni++)
                    co[row*64 + ni*16 + ml] = (_Float16)oa[mi][ni][r];
            }
        }
}

// ---------- G3: outer fc1  [4096][1024] = ctxo x ow1t, tanh -> f16 ----------
// 1024 blocks x 2 waves; tile 64x64; k-split-2; register ping-pong prefetch
__global__ __launch_bounds__(128) void k_outer_fc1_mfma(
    const _Float16* __restrict__ ctxo,   // [4096][1920]
    const _Float16* __restrict__ ow1t,   // [1024][1920]
    const float* __restrict__ ob1,
    _Float16* __restrict__ hout)         // [4096][1024]
{
    __shared__ float red[2][64][65];
    const int t = threadIdx.x, lane = t & 63, w = t >> 6;
    const int q = lane >> 4, ml = lane & 15;
    const int M0 = (blockIdx.x >> 4) * 64;
    const int N0 = (blockIdx.x & 15) * 64;
    const int kk0 = w * 960 + q * 8;
    f32x4 acc[4][4];
    #pragma unroll
    for (int mi = 0; mi < 4; mi++)
        #pragma unroll
        for (int ni = 0; ni < 4; ni++) acc[mi][ni] = (f32x4){0.f,0.f,0.f,0.f};
    f16x8 a[2][4], b[2][4];
    #pragma unroll
    for (int mi = 0; mi < 4; mi++)
        a[0][mi] = *(const f16x8*)&ctxo[(size_t)(M0 + mi*16 + ml) * 1920 + kk0];
    #pragma unroll
    for (int ni = 0; ni < 4; ni++)
        b[0][ni] = *(const f16x8*)&ow1t[(size_t)(N0 + ni*16 + ml) * 1920 + kk0];
    #pragma unroll
    for (int ks = 0; ks < 30; ks++) {
        const int cur = ks & 1, nxt = cur ^ 1;
        if (ks < 29) {
            const int kn = kk0 + (ks + 1) * 32;
            #pragma unroll
            for (int mi = 0; mi < 4; mi++)
                a[nxt][mi] = *(const f16x8*)&ctxo[(size_t)(M0 + mi*16 + ml) * 1920 + kn];
            #pragma unroll
            for (int ni = 0; ni < 4; ni++)
                b[nxt][ni] = *(const f16x8*)&ow1t[(size_t)(N0 + ni*16 + ml) * 1920 + kn];
        }
        #pragma unroll
        for (int mi = 0; mi < 4; mi++)
            #pragma unroll
            for (int ni = 0; ni < 4; ni++)
                acc[mi][ni] = __builtin_amdgcn_mfma_f32_16x16x32_f16(a[cur][mi], b[cur][ni], acc[mi][ni], 0, 0, 0);
    }
    #pragma unroll
    for (int mi = 0; mi < 4; mi++)
        #pragma unroll
        for (int ni = 0; ni < 4; ni++)
            #pragma unroll
            for (int r = 0; r < 4; r++)
                red[w][mi*16 + q*4 + r][ni*16 + ml] = acc[mi][ni][r];
    __syncthreads();
    for (int i = t; i < 4096; i += 128) {
        const int row = i >> 6, col = i & 63;
        const float s = red[0][row][col] + red[1][row][col] + ob1[N0 + col];
        hout[(size_t)(M0 + row) * 1024 + N0 + col] = (_Float16)tanh_fast(s);
    }
}

// ---------- G4a: outer fc2 main, block-level K-split-4 ----------------------
// 2176 blocks x 4 waves; tile 32x64; block kc in [0,4); wave K=256; prefetch
__global__ __launch_bounds__(256) void k_outer_fc2_mfma(
    const _Float16* __restrict__ hout,   // [1024][4096]
    const _Float16* __restrict__ ow2t,   // [1088][4096]
    float* __restrict__ part)            // [4][1024][1080]
{
    __shared__ float red[4][32][65];
    const int t = threadIdx.x, lane = t & 63, w = t >> 6;
    const int q = lane >> 4, ml = lane & 15;
    const int bid = blockIdx.x;
    const int kc = bid & 3;
    const int rest = bid >> 2;
    const int M0 = (rest / 17) * 32;
    const int N0 = (rest % 17) * 64;
    const int kk0 = kc * 1024 + w * 256 + q * 8;
    f32x4 acc[2][4];
    #pragma unroll
    for (int mi = 0; mi < 2; mi++)
        #pragma unroll
        for (int ni = 0; ni < 4; ni++) acc[mi][ni] = (f32x4){0.f,0.f,0.f,0.f};
    f16x8 a[2][2], b[2][4];
    #pragma unroll
    for (int mi = 0; mi < 2; mi++)
        a[0][mi] = *(const f16x8*)&hout[(size_t)(M0 + mi*16 + ml) * 4096 + kk0];
    #pragma unroll
    for (int ni = 0; ni < 4; ni++)
        b[0][ni] = *(const f16x8*)&ow2t[(size_t)(N0 + ni*16 + ml) * 4096 + kk0];
    #pragma unroll
    for (int ks = 0; ks < 8; ks++) {
        const int cur = ks & 1, nxt = cur ^ 1;
        if (ks < 7) {
            const int kn = kk0 + (ks + 1) * 32;
            #pragma unroll
            for (int mi = 0; mi < 2; mi++)
                a[nxt][mi] = *(const f16x8*)&hout[(size_t)(M0 + mi*16 + ml) * 4096 + kn];
            #pragma unroll
            for (int ni = 0; ni < 4; ni++)
                b[nxt][ni] = *(const f16x8*)&ow2t[(size_t)(N0 + ni*16 + ml) * 4096 + kn];
        }
        #pragma unroll
        for (int mi = 0; mi < 2; mi++)
            #pragma unroll
            for (int ni = 0; ni < 4; ni++)
                acc[mi][ni] = __builtin_amdgcn_mfma_f32_16x16x32_f16(a[cur][mi], b[cur][ni], acc[mi][ni], 0, 0, 0);
    }
    #pragma unroll
    for (int mi = 0; mi < 2; mi++)
        #pragma unroll
        for (int ni = 0; ni < 4; ni++)
            #pragma unroll
            for (int r = 0; r < 4; r++)
                red[w][mi*16 + q*4 + r][ni*16 + ml] = acc[mi][ni][r];
    __syncthreads();
    for (int i = t; i < 2048; i += 256) {
        const int row = i >> 6, col = i & 63;
        const int n = N0 + col;
        if (n < 1080) {
            const float s = red[0][row][col] + red[1][row][col] + red[2][row][col] + red[3][row][col];
            part[(size_t)kc * 1105920 + (size_t)(M0 + row) * 1080 + n] = s;
        }
    }
}

// ---------- G4b: fc2 reduce + bias ------------------------------------------
__global__ __launch_bounds__(256) void k_fc2_reduce(
    const float* __restrict__ part, const float* __restrict__ ob2,
    float* __restrict__ out)
{
    const int idx = blockIdx.x * 256 + threadIdx.x;
    if (idx >= 1105920) return;
    const int n = idx % 1080;
    out[idx] = part[idx] + part[1105920 + idx] + part[2211840 + idx]
             + part[3317760 + idx] + ob2[n];
}

extern "C" void kernel_launch(void* const* d_in, const int* in_sizes, int n_in,
                              void* d_out, int out_size, void* d_ws, size_t ws_size,
                              hipStream_t stream) {
    const float* x   = (const float*)d_in[0];
    const float* iwq = (const float*)d_in[1];
    const float* ibq = (const float*)d_in[2];
    const float* iwk = (const float*)d_in[3];
    const float* ibk = (const float*)d_in[4];
    const float* iwv = (const float*)d_in[5];
    const float* ibv = (const float*)d_in[6];
    const float* iw1 = (const float*)d_in[7];
    const float* ib1 = (const float*)d_in[8];
    const float* iw2 = (const float*)d_in[9];
    const float* ib2 = (const float*)d_in[10];
    const float* owq = (const float*)d_in[11];
    const float* obq = (const float*)d_in[12];
    const float* owk = (const float*)d_in[13];
    const float* obk = (const float*)d_in[14];
    const float* owv = (const float*)d_in[15];
    const float* obv = (const float*)d_in[16];
    const float* ow1 = (const float*)d_in[17];
    const float* ob1 = (const float*)d_in[18];
    const float* ow2 = (const float*)d_in[19];
    const float* ob2 = (const float*)d_in[20];

    char* ws = (char*)d_ws;
    _Float16* iw1t   = (_Float16*)(ws + 0);          // [256][160]
    _Float16* wqf    = (_Float16*)(ws + 98304);      // [64][8]
    _Float16* wkf    = (_Float16*)(ws + 99328);
    _Float16* wvf    = (_Float16*)(ws + 100352);
    _Float16* iw2t   = (_Float16*)(ws + 163840);     // [64][1024]
    _Float16* ow1t   = (_Float16*)(ws + 294912);     // [1024][1920]
    _Float16* ow2t   = (_Float16*)(ws + 4227072);    // [1088][4096]
    _Float16* flat   = (_Float16*)(ws + 13139968);   // [122880][160]
    float*    seq    = (float*)   (ws + 52461568);   // [30720][64]
    _Float16* owqt   = (_Float16*)(ws + 60325888);   // [4][64][64]
    _Float16* owkt   = (_Float16*)(ws + 60358656);
    _Float16* owvt   = (_Float16*)(ws + 60391424);
    _Float16* ctxo   = (_Float16*)(ws + 13139968);   // reuse (dead flat)
    float*    part   = (float*)   (ws + 13139968);   // reuse (dead ctxo), 17.7MB
    _Float16* houtb  = (_Float16*)(ws + 40000000);   // inside dead flat region
    float*    out    = (float*)d_out;

    k_prep_all       <<<dim3(1937), dim3(256), 0, stream>>>(
        iwq, ibq, iwk, ibk, iwv, ibv, iw1, iw2, ow1, ow2, owq, owk, owv,
        wqf, wkf, wvf, iw1t, iw2t, ow1t, ow2t, owqt, owkt, owvt);
    k_inner_attn_mfma<<<dim3(7680), dim3(256), 0, stream>>>(x, wqf, wkf, wvf, flat);
    k_inner_ml_mfma  <<<dim3(960),  dim3(256), 0, stream>>>(flat, iw1t, iw2t, ib1, ib2, seq);
    k_outer_attn_mfma<<<dim3(1024), dim3(256), 0, stream>>>(seq, owqt, owkt, owvt, obq, obk, obv, ctxo);
    k_outer_fc1_mfma <<<dim3(1024), dim3(128), 0, stream>>>(ctxo, ow1t, ob1, houtb);
    k_outer_fc2_mfma <<<dim3(2176), dim3(256), 0, stream>>>(houtb, ow2t, part);
    k_fc2_reduce     <<<dim3(4320), dim3(256), 0, stream>>>(part, ob2, out);
}